// Round 18
// baseline (174.372 us; speedup 1.0000x reference)
//
#include <hip/hip_runtime.h>
#include <hip/hip_bf16.h>
#include <math.h>

#define BB  4
#define SQL 2048
#define SKL 2048
#define DD  512
#define MM  8
#define NG  (BB*MM)
#define NTOK (BB*(SQL+SKL))
#define PCAP (8u*1024u*1024u)    // bf16 prob scratch cap (elements)
#define KTCAP ((size_t)DD*11264) // bf16 KcT cap (elements), 64-aligned+skewed rows
#define UCAP  (34u*1024u*1024u)  // union region bytes: S (f32) | Wqt|Wkt|Qb16|Kb16
#define PROJCAP 512
#define SCCAP   6144
#define PVCAP   512
#define SCALE 0.04419417382415922f

typedef __attribute__((ext_vector_type(8))) short short8v;
typedef __attribute__((ext_vector_type(4))) float f32x4;

__device__ __forceinline__ ushort f2b(float x) {
    union { __hip_bfloat16 h; ushort u; } cv; cv.h = __float2bfloat16(x); return cv.u;
}
__device__ __forceinline__ float b2f(ushort x) {
    union { ushort u; __hip_bfloat16 h; } cv; cv.u = x; return __bfloat162float(cv.h);
}
// tanh-form GELU: x*e/(e+1), e = exp(2*sqrt(2/pi)*(x + 0.044715 x^3)).
__device__ __forceinline__ float gelu_fast(float x) {
    float z2 = 1.5957691216057308f * x * (1.0f + 0.044715f * x * x);
    float e = __expf(fminf(z2, 40.0f));
    return x * e * __builtin_amdgcn_rcpf(e + 1.0f);
}
__device__ __forceinline__ void gload16(const ushort* g, ushort* l) {
    __builtin_amdgcn_global_load_lds(
        (const __attribute__((address_space(1))) void*)g,
        (__attribute__((address_space(3))) void*)l, 16, 0, 0);
}

// ---------------- routing: f64 accum argmax; also emits bf16 token-order Q/K ----------------
__global__ void k_route(const float* __restrict__ Q, const float* __restrict__ K,
                        const float* __restrict__ miu,
                        int* __restrict__ aq, int* __restrict__ ak,
                        ushort* __restrict__ Qb16, ushort* __restrict__ Kb16) {
    int g    = blockIdx.x * 4 + (threadIdx.x >> 6);
    int lane = threadIdx.x & 63;
    int b = g >> 12;
    int t = g & 4095;
    bool isQ = (t < SQL);
    size_t rowoff = isQ ? (size_t)(b*SQL + t) * DD : (size_t)(b*SKL + (t - SQL)) * DD;
    const float* x = (isQ ? Q : K) + rowoff;
    ushort* yb = (isQ ? Qb16 : Kb16) + rowoff;
    double acc[MM];
#pragma unroll
    for (int m = 0; m < MM; ++m) acc[m] = 0.0;
#pragma unroll
    for (int j = 0; j < 8; ++j) {
        int i = j * 64 + lane;
        float xv = x[i];
        yb[i] = f2b(xv);
#pragma unroll
        for (int m = 0; m < MM; ++m) acc[m] += (double)xv * (double)miu[m*DD + i];
    }
#pragma unroll
    for (int m = 0; m < MM; ++m) {
#pragma unroll
        for (int off = 32; off > 0; off >>= 1)
            acc[m] += __shfl_down(acc[m], off);
    }
    if (lane == 0) {
        double best = acc[0]; int bi = 0;
#pragma unroll
        for (int m = 1; m < MM; ++m) if (acc[m] > best) { best = acc[m]; bi = m; }
        if (isQ) aq[b*SQL + t] = bi; else ak[b*SKL + (t - SQL)] = bi;
    }
}

// ---------------- stable compaction into per-(b,m) index lists ----------------
__global__ void k_compact(const int* __restrict__ aq, const int* __restrict__ ak,
                          int* __restrict__ qcnt, int* __restrict__ kcnt,
                          int* __restrict__ qlist, int* __restrict__ klist) {
    int idx = blockIdx.x;
    int isK = idx >> 5;
    int g   = idx & 31;
    int b = g >> 3, m = g & 7;
    const int* a = isK ? (ak + b*SKL) : (aq + b*SQL);
    int* list = (isK ? klist : qlist) + g*SQL;
    int lane = threadIdx.x;
    int base = 0;
    for (int c = 0; c < SQL; c += 64) {
        int s = c + lane;
        bool f = (a[s] == m);
        unsigned long long mk = __ballot(f);
        int before = __popcll(mk & ((1ull << lane) - 1ull));
        if (f) list[base + before] = s;
        base += __popcll(mk);
    }
    if (lane == 0) (isK ? kcnt : qcnt)[g] = base;
}

// ---------------- offsets + compact tile work-lists ----------------
__global__ void k_soff(const int* __restrict__ qcnt, const int* __restrict__ kcnt,
                       int* __restrict__ soff, int* __restrict__ pboff,
                       int* __restrict__ qoff, int* __restrict__ koff,
                       int* __restrict__ tkoff, int* __restrict__ counts,
                       int* __restrict__ projl, int* __restrict__ scl,
                       int* __restrict__ pvl) {
    __shared__ int pbase[64], sbase[32], pvbase[32];
    int lane = threadIdx.x;
    if (lane == 0) {
        int sacc = 0, pacc = 0, qa = 0, ka = 0, ta = 0;
        for (int g = 0; g < NG; ++g) {
            soff[g] = sacc; pboff[g] = pacc; qoff[g] = qa; koff[g] = ka; tkoff[g] = ta;
            int nq = qcnt[g], nk = kcnt[g];
            int nks = ((nk + 63) & ~63) + 32;
            sacc += nq * nk; pacc += nq * nks; qa += nq; ka += nk; ta += DD * nks;
        }
        soff[NG] = sacc; pboff[NG] = pacc; qoff[NG] = qa; koff[NG] = ka; tkoff[NG] = ta;
        int pj = 0, sc = 0, pv = 0;
        for (int sg = 0; sg < 64; ++sg) {
            int n = (sg >= 32 ? kcnt : qcnt)[sg & 31];
            pbase[sg] = pj; pj += (n + 63) >> 6;      // 64-token proj tiles
        }
        for (int g = 0; g < NG; ++g) {
            int nq = qcnt[g], nk = kcnt[g];
            sbase[g] = sc; pvbase[g] = pv;
            if (nq > 0 && nk > 0) {
                sc += ((nq + 63) >> 6) * ((nk + 63) >> 6);
                pv += (nq + 31) >> 5;                 // 32-row pv tiles
            }
        }
        counts[0] = pj; counts[1] = sc; counts[2] = pv;
    }
    __syncthreads();
    {   // proj tiles: one (side,g) per lane
        int sg = lane;
        int side = sg >> 5, g = sg & 31;
        int n = (side ? kcnt : qcnt)[g];
        int ntile = (n + 63) >> 6;
        int base = pbase[sg];
        for (int ty = 0; ty < ntile; ++ty)
            projl[base + ty] = (side << 12) | (g << 7) | ty;
    }
    if (lane < 32) {   // scores + pv tiles: one g per lane (group-contiguous order)
        int g = lane;
        int nq = qcnt[g], nk = kcnt[g];
        if (nq > 0 && nk > 0) {
            int nqt = (nq + 63) >> 6, nkt = (nk + 63) >> 6;
            int idx = sbase[g];
            for (int qy = 0; qy < nqt; ++qy)
                for (int ky = 0; ky < nkt; ++ky)
                    scl[idx++] = (g << 10) | (qy << 5) | ky;
            int nqt32 = (nq + 31) >> 5;
            int pidx = pvbase[g];
            for (int qy = 0; qy < nqt32; ++qy)
                pvl[pidx++] = (g << 7) | qy;          // qy fits 7 bits (<= 64)
        }
    }
}

// W[m][d][e] (f32) -> Wt[m][e][d] (bf16), tiled transpose
__global__ void k_cvtW(const float* __restrict__ Wq, const float* __restrict__ Wk,
                       ushort* __restrict__ Wqt, ushort* __restrict__ Wkt) {
    __shared__ float tile[32][33];
    int mm = blockIdx.x; int isK = mm >> 3; int m = mm & 7;
    const float* W = (isK ? Wk : Wq) + (size_t)m * DD * DD;
    ushort* Wt = (isK ? Wkt : Wqt) + (size_t)m * DD * DD;
    int d0 = blockIdx.y * 32, e0 = blockIdx.z * 32;
    int tx = threadIdx.x, ty = threadIdx.y;   // 32 x 8
    for (int i = ty; i < 32; i += 8)
        tile[i][tx] = W[(size_t)(d0 + i) * DD + e0 + tx];
    __syncthreads();
    for (int i = ty; i < 32; i += 8)
        Wt[(size_t)(e0 + i) * DD + d0 + tx] = f2b(tile[tx][i]);
}

// ---------------- grouped expert projection: 64x128 tile, dbuf 48KB (3 blocks/CU) ----------------
// 4 waves side-by-side: each 64 rows x 32 cols (4x2 frags). Staging keeps the
// coalesced 8-row x 128B gload16 burst pattern; XOR-swizzled read/source pair.
__global__ __launch_bounds__(256) void k_proj_mfma(
        const ushort* __restrict__ Qb16, const ushort* __restrict__ Kb16,
        const ushort* __restrict__ Wqt, const ushort* __restrict__ Wkt,
        const float* __restrict__ bq, const float* __restrict__ bk,
        const int* __restrict__ qcnt, const int* __restrict__ kcnt,
        const int* __restrict__ qlist, const int* __restrict__ klist,
        const int* __restrict__ qoff, const int* __restrict__ koff,
        const int* __restrict__ tkoff, const int* __restrict__ counts,
        const int* __restrict__ projl,
        ushort* __restrict__ Qc, ushort* __restrict__ Kc, ushort* __restrict__ KcT) {
    __shared__ ushort lds[2][12288];          // per buf: As[64][64] | Bs[128][64]
    __shared__ int rows[64];
    int tid = threadIdx.x;
    int wid = tid >> 6, lane = tid & 63;
    int lr = lane & 15;
    int h = lane >> 4;                        // 0..3 (k-slot)
    int x7 = lr & 7;                          // read-side swizzle key
    int csz0 = ((h ^ x7) << 3);               // swizzled read col (ushorts), kk=0
    int csz1 = (((4 | h) ^ x7) << 3);         // kk=1
    int c0 = blockIdx.y * 128;
    int e8 = lane >> 3;                       // stage: row-within-chunk
    int glcs = (((lane & 7) ^ e8) << 3);      // stage: PRE-SWIZZLED source col (ushorts)
    int cnt = counts[0];
    int vbid = (blockIdx.x & 7) * 32 + (blockIdx.x >> 3);   // XCD-chunked (256 blocks)

    for (int slot = vbid; slot < cnt; slot += gridDim.x) {
        int e = projl[slot];
        int isK = (e >> 12) & 1, g = (e >> 7) & 31, ty = e & 127;
        int n = (isK ? kcnt : qcnt)[g];
        int obase = (isK ? koff : qoff)[g];
        int b = g >> 3, m = g & 7;
        const ushort* Xtok = (isK ? Kb16 : Qb16) + (size_t)b * SQL * DD;
        const ushort* Wt = (isK ? Wkt : Wqt) + (size_t)m * DD * DD;
        const float* bias = (isK ? bk : bq) + m * DD;
        const int* list = (isK ? klist : qlist) + g * SQL;
        int t0 = ty * 64;

        __syncthreads();                      // prev slot done with rows[]
        if (tid < 64) rows[tid] = list[min(t0 + tid, n - 1)];
        __syncthreads();

        auto STAGE = [&](int buf, int kt) {
            int d0 = kt * 64;
            ushort* As = lds[buf];
            ushort* Bs = lds[buf] + 4096;
#pragma unroll
            for (int j0 = 0; j0 < 6; ++j0) {
                int j = wid + j0 * 4;         // 0..23: A chunks 0-7, B chunks 8-23
                if (j < 8) {
                    int rtok = rows[j*8 + e8];
                    gload16(Xtok + (size_t)rtok * DD + d0 + glcs, As + j*512);
                } else {
                    int jb = j - 8;
                    int rB = c0 + jb*8 + e8;
                    gload16(Wt + (size_t)rB * DD + d0 + glcs, Bs + jb*512);
                }
            }
        };

        f32x4 acc[4][2];
#pragma unroll
        for (int t = 0; t < 4; ++t)
#pragma unroll
            for (int c = 0; c < 2; ++c) acc[t][c] = (f32x4){0.f, 0.f, 0.f, 0.f};

        STAGE(0, 0);
        __syncthreads();
        for (int kt = 0; kt < 8; ++kt) {
            int cur = kt & 1;
            if (kt < 7) STAGE(cur ^ 1, kt + 1);   // prefetch next K-step (overlaps MFMA)
            const ushort* As = lds[cur];
            const ushort* Bs = lds[cur] + 4096;
#pragma unroll
            for (int kk = 0; kk < 2; ++kk) {
                int csz = kk ? csz1 : csz0;
                short8v a[4], bb[2];
#pragma unroll
                for (int t = 0; t < 4; ++t)
                    a[t] = *(const short8v*)(As + (t*16 + lr)*64 + csz);
#pragma unroll
                for (int c = 0; c < 2; ++c)
                    bb[c] = *(const short8v*)(Bs + (wid*32 + c*16 + lr)*64 + csz);
#pragma unroll
                for (int t = 0; t < 4; ++t)
#pragma unroll
                    for (int c = 0; c < 2; ++c)
                        acc[t][c] = __builtin_amdgcn_mfma_f32_16x16x32_bf16(a[t], bb[c], acc[t][c], 0, 0, 0);
            }
            __syncthreads();                  // drains prefetch vmcnt; buf swap safe
        }

        float bcache[2];
#pragma unroll
        for (int c = 0; c < 2; ++c) bcache[c] = bias[c0 + wid*32 + c*16 + lr];

        int rb = (lane >> 4) << 2;
        int nk2 = kcnt[g];
        int nks = ((nk2 + 63) & ~63) + 32;    // 64-aligned + skewed KcT row stride
        int tk = tkoff[g];
        ushort* Yc = isK ? Kc : Qc;
#pragma unroll
        for (int t = 0; t < 4; ++t) {
            int grow = ty*64 + t*16 + rb;            // group-relative row of r=0
#pragma unroll
            for (int c = 0; c < 2; ++c) {
                int col = c0 + wid*32 + c*16 + lr;
                float v[4];
#pragma unroll
                for (int r = 0; r < 4; ++r) v[r] = gelu_fast(acc[t][c][r] + bcache[c]);
                if (!isK) {
#pragma unroll
                    for (int r = 0; r < 4; ++r)
                        if (grow + r < n)
                            Yc[(size_t)(obase + grow + r) * DD + col] = f2b(v[r] * SCALE);
                } else {
#pragma unroll
                    for (int r = 0; r < 4; ++r)
                        if (grow + r < n)
                            Yc[(size_t)(obase + grow + r) * DD + col] = f2b(v[r]);
                    size_t taddr = (size_t)tk + (size_t)col * nks + grow;
                    if (grow + 3 < n) {
                        ushort4 o; o.x = f2b(v[0]); o.y = f2b(v[1]); o.z = f2b(v[2]); o.w = f2b(v[3]);
                        *(ushort4*)(KcT + taddr) = o;
                    } else {
#pragma unroll
                        for (int r = 0; r < 4; ++r)
                            if (grow + r < n) KcT[taddr + r] = f2b(v[r]);
                    }
                }
            }
        }
    }
}

// ---------------- mean of Kp over all keys (fallback value), two-stage ----------------
__global__ void k_meanpart(const ushort* __restrict__ Kc, const int* __restrict__ koff,
                           float* __restrict__ part) {
    int b = blockIdx.x, ch = blockIdx.y;      // 32 chunks of 64 rows
    int d = threadIdx.x;                      // 256 threads -> 2 cols each
    int base = koff[b*8] + ch * 64;
    float a0 = 0.f, a1 = 0.f;
    for (int t = 0; t < 64; ++t) {
        const ushort* row = Kc + (size_t)(base + t) * DD;
        a0 += b2f(row[d]); a1 += b2f(row[d + 256]);
    }
    part[((size_t)(b*32 + ch))*DD + d]       = a0;
    part[((size_t)(b*32 + ch))*DD + d + 256] = a1;
}
__global__ void k_meanfinal(const float* __restrict__ part, float* __restrict__ meanV) {
    int b = blockIdx.x; int d = threadIdx.x;  // 512 threads
    float a0 = 0.f;
    for (int ch = 0; ch < 32; ++ch)
        a0 += part[((size_t)(b*32 + ch))*DD + d];
    meanV[b*DD + d] = a0 * (1.0f/SKL);
}

// ---------------- grouped scores S = Qc @ Kc^T (scale pre-folded into Qc) ----------------
__global__ __launch_bounds__(256) void k_scores_mfma(
        const ushort* __restrict__ Qc, const ushort* __restrict__ Kc,
        const int* __restrict__ qcnt, const int* __restrict__ kcnt,
        const int* __restrict__ qoff, const int* __restrict__ koff,
        const int* __restrict__ soff, const int* __restrict__ counts,
        const int* __restrict__ scl, float* __restrict__ S) {
    int tid = threadIdx.x, wid = tid >> 6, lane = tid & 63;
    int wr = wid >> 1, wc = wid & 1;
    int lr = lane & 15, lk = (lane >> 4) * 8;
    int cnt = counts[1];
    int vbid = (blockIdx.x & 7) * 128 + (blockIdx.x >> 3);  // XCD-chunked (1024 blocks)
    for (int slot = vbid; slot < cnt; slot += gridDim.x) {
        int e = scl[slot];
        int g = (e >> 10) & 31, qt = ((e >> 5) & 31) * 64, kt = (e & 31) * 64;
        int nq = qcnt[g], nk = kcnt[g];
        int qb = qoff[g], kb = koff[g];

        const ushort* ap[2];
#pragma unroll
        for (int t = 0; t < 2; ++t)
            ap[t] = Qc + (size_t)(qb + min(qt + wr*32 + t*16 + lr, nq - 1)) * DD + lk;
        const ushort* bp[2];
#pragma unroll
        for (int c = 0; c < 2; ++c)
            bp[c] = Kc + (size_t)(kb + min(kt + wc*32 + c*16 + lr, nk - 1)) * DD + lk;

        f32x4 acc[2][2];
#pragma unroll
        for (int t = 0; t < 2; ++t)
#pragma unroll
            for (int c = 0; c < 2; ++c) acc[t][c] = (f32x4){0.f, 0.f, 0.f, 0.f};

        short8v a[2], bb[2], an[2], bn[2];
#pragma unroll
        for (int t = 0; t < 2; ++t) a[t]  = *(const short8v*)(ap[t]);
#pragma unroll
        for (int c = 0; c < 2; ++c) bb[c] = *(const short8v*)(bp[c]);
        for (int d0 = 0; d0 < DD; d0 += 32) {
            int dn = d0 + 32;
            if (dn < DD) {
#pragma unroll
                for (int t = 0; t < 2; ++t) an[t] = *(const short8v*)(ap[t] + dn);
#pragma unroll
                for (int c = 0; c < 2; ++c) bn[c] = *(const short8v*)(bp[c] + dn);
            }
#pragma unroll
            for (int t = 0; t < 2; ++t)
#pragma unroll
                for (int c = 0; c < 2; ++c)
                    acc[t][c] = __builtin_amdgcn_mfma_f32_16x16x32_bf16(a[t], bb[c], acc[t][c], 0, 0, 0);
#pragma unroll
            for (int t = 0; t < 2; ++t) a[t] = an[t];
#pragma unroll
            for (int c = 0; c < 2; ++c) bb[c] = bn[c];
        }

        int sbase = soff[g];
        int rb = (lane >> 4) << 2;
#pragma unroll
        for (int t = 0; t < 2; ++t) {
#pragma unroll
            for (int r = 0; r < 4; ++r) {
                int gr = qt + wr*32 + t*16 + rb + r;
                if (gr >= nq) continue;
#pragma unroll
                for (int c = 0; c < 2; ++c) {
                    int gc = kt + wc*32 + c*16 + lr;
                    if (gc < nk) S[(size_t)sbase + (size_t)gr*nk + gc] = acc[t][c][r];
                }
            }
        }
    }
}

// ---------------- softmax rows -> bf16 probs, zero-padded to nk64, skewed stride ----------------
__global__ void k_softmax(const int* __restrict__ qcnt, const int* __restrict__ kcnt,
                          const int* __restrict__ soff, const int* __restrict__ pboff,
                          float* __restrict__ S, ushort* __restrict__ Pb) {
    int g = blockIdx.x;
    int nq = qcnt[g], nk = kcnt[g];
    if (nk == 0) return;
    int wid = threadIdx.x >> 6, lane = threadIdx.x & 63;
    int nk64 = (nk + 63) & ~63;
    int nks = nk64 + 32;
    for (int row = blockIdx.y * 16 + wid; row < nq; row += 512) {
        float* p = S + (size_t)soff[g] + (size_t)row * nk;
        ushort* pr = Pb + (size_t)pboff[g] + (size_t)row * nks;
        float mx = -3.4e38f;
        for (int c = lane; c < nk; c += 64) mx = fmaxf(mx, p[c]);
#pragma unroll
        for (int off = 32; off > 0; off >>= 1) mx = fmaxf(mx, __shfl_xor(mx, off));
        float sm = 0.f;
        for (int c = lane; c < nk; c += 64) { float e = __expf(p[c] - mx); p[c] = e; sm += e; }
#pragma unroll
        for (int off = 32; off > 0; off >>= 1) sm += __shfl_xor(sm, off);
        float inv = 1.0f / sm;
        for (int c = lane; c < nk64; c += 64) {
            float v = (c < nk) ? p[c] * inv : 0.f;
            pr[c] = f2b(v);
        }
    }
}

// ---------------- PV: O = P @ Kc via KcT, LDS-staged bf16 MFMA, epilogue += Q ----------------
__global__ __launch_bounds__(256) void k_pv_mfma(
        const ushort* __restrict__ Pb, const ushort* __restrict__ KcT,
        const float* __restrict__ Q,
        const int* __restrict__ qcnt, const int* __restrict__ kcnt,
        const int* __restrict__ tkoff, const int* __restrict__ pboff,
        const int* __restrict__ qlist, const int* __restrict__ counts,
        const int* __restrict__ pvl, float* __restrict__ out) {
    __shared__ ushort plds[2][2048];          // 32 rows x 64 keys
    __shared__ ushort klds[2][8192];          // 128 cols x 64 keys
    int tid = threadIdx.x, wid = tid >> 6, lane = tid & 63;
    int lr = lane & 15;
    int h  = lane >> 4;
    int x7 = lr & 7;
    int csz0 = ((h ^ x7) << 3);
    int csz1 = (((4 | h) ^ x7) << 3);
    int e8 = lane >> 3;                       // row-within-chunk (0..7)
    int glcs = (((lane & 7) ^ e8) << 3);      // pre-swizzled source col (ushorts)
    int cnt = counts[2];
    int vbid = (blockIdx.x & 7) * 32 + (blockIdx.x >> 3);   // XCD-chunked (256 blocks)
    int dt = blockIdx.y * 128;

    for (int slot = vbid; slot < cnt; slot += gridDim.x) {
        int e = pvl[slot];
        int g = e >> 7, qt = (e & 127) * 32;
        int nq = qcnt[g], nk = kcnt[g];
        int b = g >> 3;
        int nk64 = (nk + 63) & ~63;
        int nks = nk64 + 32;
        int tk = tkoff[g], pbase = pboff[g];

        const ushort* psrc = Pb + (size_t)pbase
            + (size_t)min(qt + wid*8 + e8, nq - 1) * nks + glcs;
        const ushort* ksrc[4];
#pragma unroll
        for (int p = 0; p < 4; ++p) {
            int col = (wid + p*4) * 8 + e8;   // 0..127
            ksrc[p] = KcT + (size_t)tk + (size_t)(dt + col) * nks + glcs;
        }

        auto STAGE = [&](int buf, int kt) {
            int k0 = kt * 64;
            gload16(psrc + k0, &plds[buf][wid * 512]);
#pragma unroll
            for (int p = 0; p < 4; ++p)
                gload16(ksrc[p] + k0, &klds[buf][(wid + p*4) * 512]);
        };

        f32x4 acc[2][2];
#pragma unroll
        for (int t = 0; t < 2; ++t)
#pragma unroll
            for (int c = 0; c < 2; ++c) acc[t][c] = (f32x4){0.f, 0.f, 0.f, 0.f};

        int nt = nk64 >> 6;
        __syncthreads();                      // prev slot done with LDS
        STAGE(0, 0);
        __syncthreads();
        for (int kt = 0; kt < nt; ++kt) {
            int cur = kt & 1;
            if (kt + 1 < nt) STAGE(cur ^ 1, kt + 1);
            const ushort* P_ = plds[cur];
            const ushort* K_ = klds[cur];
#pragma unroll
            for (int kk = 0; kk < 2; ++kk) {
                int csz = kk ? csz1 : csz0;
                short8v a[2], bb[2];
#pragma unroll
                for (int t = 0; t < 2; ++t)
                    a[t] = *(const short8v*)(P_ + (t*16 + lr)*64 + csz);
#pragma unroll
                for (int c = 0; c < 2; ++c)
                    bb[c] = *(const short8v*)(K_ + (wid*32 + c*16 + lr)*64 + csz);
#pragma unroll
                for (int t = 0; t < 2; ++t)
#pragma unroll
                    for (int c = 0; c < 2; ++c)
                        acc[t][c] = __builtin_amdgcn_mfma_f32_16x16x32_bf16(a[t], bb[c], acc[t][c], 0, 0, 0);
            }
            __syncthreads();                  // prefetch drained; buf swap safe
        }

        int rb = (lane >> 4) << 2;
#pragma unroll
        for (int t = 0; t < 2; ++t) {
#pragma unroll
            for (int r = 0; r < 4; ++r) {
                int gr = qt + t*16 + rb + r;
                if (gr >= nq) continue;
                int qrow = qlist[g*SQL + gr];
                size_t obase = ((size_t)(b*SQL) + qrow) * DD;
#pragma unroll
                for (int c = 0; c < 2; ++c) {
                    size_t o = obase + dt + wid*32 + c*16 + lr;
                    out[o] = acc[t][c][r] + Q[o];
                }
            }
        }
    }
}

// ---------------- fallback for groups with no keys: O = mean(Kp) + Q ----------------
__global__ void k_fallback(const float* __restrict__ Q, const float* __restrict__ meanV,
                           const int* __restrict__ qcnt, const int* __restrict__ kcnt,
                           const int* __restrict__ qlist, float* __restrict__ out) {
    int g = blockIdx.x;
    if (kcnt[g] != 0) return;
    int nq = qcnt[g]; int b = g >> 3;
    int r0 = blockIdx.y * 256;
    int rend = min(r0 + 256, nq);
    for (int r = r0; r < rend; ++r) {
        int qrow = qlist[g*SQL + r];
        size_t base = ((size_t)(b*SQL) + qrow) * DD;
        for (int d = threadIdx.x; d < DD; d += 256)
            out[base + d] = meanV[b*DD + d] + Q[base + d];
    }
}

extern "C" void kernel_launch(void* const* d_in, const int* in_sizes, int n_in,
                              void* d_out, int out_size, void* d_ws, size_t ws_size,
                              hipStream_t stream) {
    (void)in_sizes; (void)n_in; (void)out_size; (void)ws_size;
    const float* Q   = (const float*)d_in[0];
    const float* K   = (const float*)d_in[1];
    // d_in[2] (V) unused: Vp == Kp in the reference.
    const float* miu = (const float*)d_in[3];
    const float* Wq  = (const float*)d_in[4];
    const float* bq  = (const float*)d_in[5];
    const float* Wk  = (const float*)d_in[6];
    const float* bk  = (const float*)d_in[7];
    float* out = (float*)d_out;
    char* ws = (char*)d_ws;

    size_t off = 0;
    auto alloc = [&](size_t bytes) { size_t o = off; off += (bytes + 255) & ~(size_t)255; return o; };
    int*   aq     = (int*)  (ws + alloc((size_t)BB*SQL*4));
    int*   ak     = (int*)  (ws + alloc((size_t)BB*SKL*4));
    int*   qcnt   = (int*)  (ws + alloc(NG*4));
    int*   kcnt   = (int*)  (ws + alloc(NG*4));
    int*   soff   = (int*)  (ws + alloc((NG+1)*4));
    int*   pboff  = (int*)  (ws + alloc((NG+1)*4));
    int*   qoff   = (int*)  (ws + alloc((NG+1)*4));
    int*   koff   = (int*)  (ws + alloc((NG+1)*4));
    int*   tkoff  = (int*)  (ws + alloc((NG+1)*4));
    int*   counts = (int*)  (ws + alloc(16*4));
    int*   projl  = (int*)  (ws + alloc(PROJCAP*4));
    int*   scl    = (int*)  (ws + alloc(SCCAP*4));
    int*   pvl    = (int*)  (ws + alloc(PVCAP*4));
    int*   qlist  = (int*)  (ws + alloc((size_t)NG*SQL*4));
    int*   klist  = (int*)  (ws + alloc((size_t)NG*SKL*4));
    float* part   = (float*)(ws + alloc((size_t)BB*32*DD*4));
    float* meanV  = (float*)(ws + alloc((size_t)BB*DD*4));
    ushort* Qc    = (ushort*)(ws + alloc((size_t)BB*SQL*DD*2));
    ushort* Kc    = (ushort*)(ws + alloc((size_t)BB*SKL*DD*2));
    ushort* KcT   = (ushort*)(ws + alloc(KTCAP*2));
    ushort* Pb    = (ushort*)(ws + alloc((size_t)PCAP*2));
    // Union region (34 MB): bf16 staging Wqt|Wkt|Qb16|Kb16 (dead after proj), then S (f32).
    size_t uoff = alloc((size_t)UCAP);
    float* S     = (float*)(ws + uoff);
    ushort* Wqt  = (ushort*)(ws + uoff);
    ushort* Wkt  = Wqt  + (size_t)MM*DD*DD;
    ushort* Qb16 = Wkt  + (size_t)MM*DD*DD;
    ushort* Kb16 = Qb16 + (size_t)BB*SQL*DD;

    k_route     <<<NTOK/4, 256, 0, stream>>>(Q, K, miu, aq, ak, Qb16, Kb16);
    k_compact   <<<NG*2, 64, 0, stream>>>(aq, ak, qcnt, kcnt, qlist, klist);
    k_soff      <<<1, 64, 0, stream>>>(qcnt, kcnt, soff, pboff, qoff, koff, tkoff,
                                       counts, projl, scl, pvl);
    k_cvtW      <<<dim3(16, 16, 16), dim3(32, 8), 0, stream>>>(Wq, Wk, Wqt, Wkt);
    k_proj_mfma <<<dim3(256, 4), 256, 0, stream>>>(Qb16, Kb16, Wqt, Wkt, bq, bk,
                                                   qcnt, kcnt, qlist, klist, qoff, koff,
                                                   tkoff, counts, projl, Qc, Kc, KcT);
    k_meanpart  <<<dim3(BB, 32), 256, 0, stream>>>(Kc, koff, part);
    k_meanfinal <<<BB, 512, 0, stream>>>(part, meanV);
    k_scores_mfma<<<1024, 256, 0, stream>>>(Qc, Kc, qcnt, kcnt, qoff, koff, soff,
                                            counts, scl, S);
    k_softmax   <<<dim3(NG, 32), 1024, 0, stream>>>(qcnt, kcnt, soff, pboff, S, Pb);
    k_pv_mfma   <<<dim3(256, 4), 256, 0, stream>>>(Pb, KcT, Q, qcnt, kcnt, tkoff, pboff,
                                                   qlist, counts, pvl, out);
    k_fallback  <<<dim3(NG, 8), 256, 0, stream>>>(Q, meanV, qcnt, kcnt, qlist, out);
}

// Round 19
// 163.783 us; speedup vs baseline: 1.0647x; 1.0647x over previous
//
#include <hip/hip_runtime.h>
#include <hip/hip_bf16.h>
#include <math.h>

#define BB  4
#define SQL 2048
#define SKL 2048
#define DD  512
#define MM  8
#define NG  (BB*MM)
#define NTOK (BB*(SQL+SKL))
#define PCAP (8u*1024u*1024u)    // bf16 prob scratch cap (elements)
#define KTCAP ((size_t)DD*11264) // bf16 KcT cap (elements), 64-aligned+skewed rows
#define UCAP  (34u*1024u*1024u)  // union region bytes: S (f32) | Wqt|Wkt|Qb16|Kb16
#define PROJCAP 512
#define SCCAP   6144
#define PVCAP   512
#define SCALE 0.04419417382415922f

typedef __attribute__((ext_vector_type(8))) short short8v;
typedef __attribute__((ext_vector_type(4))) float f32x4;

__device__ __forceinline__ ushort f2b(float x) {
    union { __hip_bfloat16 h; ushort u; } cv; cv.h = __float2bfloat16(x); return cv.u;
}
__device__ __forceinline__ float b2f(ushort x) {
    union { ushort u; __hip_bfloat16 h; } cv; cv.u = x; return __bfloat162float(cv.h);
}
// tanh-form GELU: x*e/(e+1), e = exp(2*sqrt(2/pi)*(x + 0.044715 x^3)).
__device__ __forceinline__ float gelu_fast(float x) {
    float z2 = 1.5957691216057308f * x * (1.0f + 0.044715f * x * x);
    float e = __expf(fminf(z2, 40.0f));
    return x * e * __builtin_amdgcn_rcpf(e + 1.0f);
}
__device__ __forceinline__ void gload16(const ushort* g, ushort* l) {
    __builtin_amdgcn_global_load_lds(
        (const __attribute__((address_space(1))) void*)g,
        (__attribute__((address_space(3))) void*)l, 16, 0, 0);
}

// ---------------- routing: f64 accum argmax; also emits bf16 token-order Q/K ----------------
__global__ void k_route(const float* __restrict__ Q, const float* __restrict__ K,
                        const float* __restrict__ miu,
                        int* __restrict__ aq, int* __restrict__ ak,
                        ushort* __restrict__ Qb16, ushort* __restrict__ Kb16) {
    int g    = blockIdx.x * 4 + (threadIdx.x >> 6);
    int lane = threadIdx.x & 63;
    int b = g >> 12;
    int t = g & 4095;
    bool isQ = (t < SQL);
    size_t rowoff = isQ ? (size_t)(b*SQL + t) * DD : (size_t)(b*SKL + (t - SQL)) * DD;
    const float* x = (isQ ? Q : K) + rowoff;
    ushort* yb = (isQ ? Qb16 : Kb16) + rowoff;
    double acc[MM];
#pragma unroll
    for (int m = 0; m < MM; ++m) acc[m] = 0.0;
#pragma unroll
    for (int j = 0; j < 8; ++j) {
        int i = j * 64 + lane;
        float xv = x[i];
        yb[i] = f2b(xv);
#pragma unroll
        for (int m = 0; m < MM; ++m) acc[m] += (double)xv * (double)miu[m*DD + i];
    }
#pragma unroll
    for (int m = 0; m < MM; ++m) {
#pragma unroll
        for (int off = 32; off > 0; off >>= 1)
            acc[m] += __shfl_down(acc[m], off);
    }
    if (lane == 0) {
        double best = acc[0]; int bi = 0;
#pragma unroll
        for (int m = 1; m < MM; ++m) if (acc[m] > best) { best = acc[m]; bi = m; }
        if (isQ) aq[b*SQL + t] = bi; else ak[b*SKL + (t - SQL)] = bi;
    }
}

// ---------------- stable compaction into per-(b,m) index lists ----------------
__global__ void k_compact(const int* __restrict__ aq, const int* __restrict__ ak,
                          int* __restrict__ qcnt, int* __restrict__ kcnt,
                          int* __restrict__ qlist, int* __restrict__ klist) {
    int idx = blockIdx.x;
    int isK = idx >> 5;
    int g   = idx & 31;
    int b = g >> 3, m = g & 7;
    const int* a = isK ? (ak + b*SKL) : (aq + b*SQL);
    int* list = (isK ? klist : qlist) + g*SQL;
    int lane = threadIdx.x;
    int base = 0;
    for (int c = 0; c < SQL; c += 64) {
        int s = c + lane;
        bool f = (a[s] == m);
        unsigned long long mk = __ballot(f);
        int before = __popcll(mk & ((1ull << lane) - 1ull));
        if (f) list[base + before] = s;
        base += __popcll(mk);
    }
    if (lane == 0) (isK ? kcnt : qcnt)[g] = base;
}

// ---------------- offsets + compact tile work-lists ----------------
__global__ void k_soff(const int* __restrict__ qcnt, const int* __restrict__ kcnt,
                       int* __restrict__ soff, int* __restrict__ pboff,
                       int* __restrict__ qoff, int* __restrict__ koff,
                       int* __restrict__ tkoff, int* __restrict__ counts,
                       int* __restrict__ projl, int* __restrict__ scl,
                       int* __restrict__ pvl) {
    __shared__ int pbase[64], sbase[32], pvbase[32];
    int lane = threadIdx.x;
    if (lane == 0) {
        int sacc = 0, pacc = 0, qa = 0, ka = 0, ta = 0;
        for (int g = 0; g < NG; ++g) {
            soff[g] = sacc; pboff[g] = pacc; qoff[g] = qa; koff[g] = ka; tkoff[g] = ta;
            int nq = qcnt[g], nk = kcnt[g];
            int nks = ((nk + 63) & ~63) + 32;
            sacc += nq * nk; pacc += nq * nks; qa += nq; ka += nk; ta += DD * nks;
        }
        soff[NG] = sacc; pboff[NG] = pacc; qoff[NG] = qa; koff[NG] = ka; tkoff[NG] = ta;
        int pj = 0, sc = 0, pv = 0;
        for (int sg = 0; sg < 64; ++sg) {
            int n = (sg >= 32 ? kcnt : qcnt)[sg & 31];
            pbase[sg] = pj; pj += (n + 127) >> 7;     // 128-token proj tiles
        }
        for (int g = 0; g < NG; ++g) {
            int nq = qcnt[g], nk = kcnt[g];
            sbase[g] = sc; pvbase[g] = pv;
            if (nq > 0 && nk > 0) {
                sc += ((nq + 63) >> 6) * ((nk + 63) >> 6);
                pv += (nq + 31) >> 5;                 // 32-row pv tiles
            }
        }
        counts[0] = pj; counts[1] = sc; counts[2] = pv;
    }
    __syncthreads();
    {   // proj tiles: one (side,g) per lane
        int sg = lane;
        int side = sg >> 5, g = sg & 31;
        int n = (side ? kcnt : qcnt)[g];
        int ntile = (n + 127) >> 7;
        int base = pbase[sg];
        for (int ty = 0; ty < ntile; ++ty)
            projl[base + ty] = (side << 11) | (g << 6) | ty;
    }
    if (lane < 32) {   // scores + pv tiles: one g per lane (group-contiguous order)
        int g = lane;
        int nq = qcnt[g], nk = kcnt[g];
        if (nq > 0 && nk > 0) {
            int nqt = (nq + 63) >> 6, nkt = (nk + 63) >> 6;
            int idx = sbase[g];
            for (int qy = 0; qy < nqt; ++qy)
                for (int ky = 0; ky < nkt; ++ky)
                    scl[idx++] = (g << 10) | (qy << 5) | ky;
            int nqt32 = (nq + 31) >> 5;
            int pidx = pvbase[g];
            for (int qy = 0; qy < nqt32; ++qy)
                pvl[pidx++] = (g << 7) | qy;          // qy fits 7 bits (<= 64)
        }
    }
}

// W[m][d][e] (f32) -> Wt[m][e][d] (bf16), tiled transpose
__global__ void k_cvtW(const float* __restrict__ Wq, const float* __restrict__ Wk,
                       ushort* __restrict__ Wqt, ushort* __restrict__ Wkt) {
    __shared__ float tile[32][33];
    int mm = blockIdx.x; int isK = mm >> 3; int m = mm & 7;
    const float* W = (isK ? Wk : Wq) + (size_t)m * DD * DD;
    ushort* Wt = (isK ? Wkt : Wqt) + (size_t)m * DD * DD;
    int d0 = blockIdx.y * 32, e0 = blockIdx.z * 32;
    int tx = threadIdx.x, ty = threadIdx.y;   // 32 x 8
    for (int i = ty; i < 32; i += 8)
        tile[i][tx] = W[(size_t)(d0 + i) * DD + e0 + tx];
    __syncthreads();
    for (int i = ty; i < 32; i += 8)
        Wt[(size_t)(e0 + i) * DD + d0 + tx] = f2b(tile[tx][i]);
}

// ---------------- grouped expert projection: 2-phase dbuf + XOR-swizzled LDS ----------------
// A-operand gathered DIRECTLY from token-order bf16 via per-lane gload16 source
// addresses (LDS dest stays linear). XCD-chunked swizzle (192 x-blocks).
__global__ __launch_bounds__(256) void k_proj_mfma(
        const ushort* __restrict__ Qb16, const ushort* __restrict__ Kb16,
        const ushort* __restrict__ Wqt, const ushort* __restrict__ Wkt,
        const float* __restrict__ bq, const float* __restrict__ bk,
        const int* __restrict__ qcnt, const int* __restrict__ kcnt,
        const int* __restrict__ qlist, const int* __restrict__ klist,
        const int* __restrict__ qoff, const int* __restrict__ koff,
        const int* __restrict__ tkoff, const int* __restrict__ counts,
        const int* __restrict__ projl,
        ushort* __restrict__ Qc, ushort* __restrict__ Kc, ushort* __restrict__ KcT) {
    __shared__ ushort lds[2][16384];          // per buf: As[128][64] | Bs[128][64]
    __shared__ int rows[128];
    int tid = threadIdx.x;
    int wid = tid >> 6, lane = tid & 63;
    int wr = wid >> 1, wc = wid & 1;
    int lr = lane & 15;
    int h = lane >> 4;                        // 0..3 (k-slot)
    int x7 = lr & 7;                          // read-side swizzle key
    int csz0 = ((h ^ x7) << 3);               // swizzled read col (ushorts), kk=0
    int csz1 = (((4 | h) ^ x7) << 3);         // kk=1
    int c0 = blockIdx.y * 128;
    int e8 = lane >> 3;                       // stage: row-within-chunk
    int glcs = (((lane & 7) ^ e8) << 3);      // stage: PRE-SWIZZLED source col (ushorts)
    int cnt = counts[0];
    int vbid = (blockIdx.x & 7) * 24 + (blockIdx.x >> 3);   // XCD-chunked (192 blocks)

    for (int slot = vbid; slot < cnt; slot += gridDim.x) {
        int e = projl[slot];
        int isK = (e >> 11) & 1, g = (e >> 6) & 31, ty = e & 63;
        int n = (isK ? kcnt : qcnt)[g];
        int obase = (isK ? koff : qoff)[g];
        int b = g >> 3, m = g & 7;
        const ushort* Xtok = (isK ? Kb16 : Qb16) + (size_t)b * SQL * DD;
        const ushort* Wt = (isK ? Wkt : Wqt) + (size_t)m * DD * DD;
        const float* bias = (isK ? bk : bq) + m * DD;
        const int* list = (isK ? klist : qlist) + g * SQL;
        int t0 = ty * 128;

        __syncthreads();                      // prev slot done with rows[]
        if (tid < 128) rows[tid] = list[min(t0 + tid, n - 1)];
        __syncthreads();

        auto STAGE = [&](int buf, int kt) {
            int d0 = kt * 64;
            ushort* As = lds[buf];
            ushort* Bs = lds[buf] + 8192;
#pragma unroll
            for (int j0 = 0; j0 < 4; ++j0) {
                int j = wid + j0 * 4;         // chunk 0..15 (8 rows each)
                int rtok = rows[j*8 + e8];
                gload16(Xtok + (size_t)rtok * DD + d0 + glcs, As + j*512);
                int rB = c0 + j*8 + e8;
                gload16(Wt + (size_t)rB * DD + d0 + glcs, Bs + j*512);
            }
        };

        f32x4 acc[4][4];
#pragma unroll
        for (int t = 0; t < 4; ++t)
#pragma unroll
            for (int c = 0; c < 4; ++c) acc[t][c] = (f32x4){0.f, 0.f, 0.f, 0.f};

        STAGE(0, 0);
        __syncthreads();
        for (int kt = 0; kt < 8; ++kt) {
            int cur = kt & 1;
            if (kt < 7) STAGE(cur ^ 1, kt + 1);   // prefetch next K-step (overlaps MFMA)
            const ushort* As = lds[cur];
            const ushort* Bs = lds[cur] + 8192;
#pragma unroll
            for (int kk = 0; kk < 2; ++kk) {
                int csz = kk ? csz1 : csz0;
                short8v a[4], bb[4];
#pragma unroll
                for (int t = 0; t < 4; ++t)
                    a[t] = *(const short8v*)(As + (wr*64 + t*16 + lr)*64 + csz);
#pragma unroll
                for (int c = 0; c < 4; ++c)
                    bb[c] = *(const short8v*)(Bs + (wc*64 + c*16 + lr)*64 + csz);
#pragma unroll
                for (int t = 0; t < 4; ++t)
#pragma unroll
                    for (int c = 0; c < 4; ++c)
                        acc[t][c] = __builtin_amdgcn_mfma_f32_16x16x32_bf16(a[t], bb[c], acc[t][c], 0, 0, 0);
            }
            __syncthreads();                  // drains prefetch vmcnt; buf swap safe
        }

        float bcache[4];
#pragma unroll
        for (int c = 0; c < 4; ++c) bcache[c] = bias[c0 + wc*64 + c*16 + lr];

        int rb = (lane >> 4) << 2;
        int nk2 = kcnt[g];
        int nks = ((nk2 + 63) & ~63) + 32;    // 64-aligned + skewed KcT row stride
        int tk = tkoff[g];
        ushort* Yc = isK ? Kc : Qc;
#pragma unroll
        for (int t = 0; t < 4; ++t) {
            int grow = ty*128 + wr*64 + t*16 + rb;   // group-relative row of r=0
#pragma unroll
            for (int c = 0; c < 4; ++c) {
                int col = c0 + wc*64 + c*16 + lr;
                float v[4];
#pragma unroll
                for (int r = 0; r < 4; ++r) v[r] = gelu_fast(acc[t][c][r] + bcache[c]);
                if (!isK) {
#pragma unroll
                    for (int r = 0; r < 4; ++r)
                        if (grow + r < n)
                            Yc[(size_t)(obase + grow + r) * DD + col] = f2b(v[r] * SCALE);
                } else {
#pragma unroll
                    for (int r = 0; r < 4; ++r)
                        if (grow + r < n)
                            Yc[(size_t)(obase + grow + r) * DD + col] = f2b(v[r]);
                    size_t taddr = (size_t)tk + (size_t)col * nks + grow;
                    if (grow + 3 < n) {
                        ushort4 o; o.x = f2b(v[0]); o.y = f2b(v[1]); o.z = f2b(v[2]); o.w = f2b(v[3]);
                        *(ushort4*)(KcT + taddr) = o;
                    } else {
#pragma unroll
                        for (int r = 0; r < 4; ++r)
                            if (grow + r < n) KcT[taddr + r] = f2b(v[r]);
                    }
                }
            }
        }
    }
}

// ---------------- mean of Kp over all keys (fallback value), two-stage ----------------
__global__ void k_meanpart(const ushort* __restrict__ Kc, const int* __restrict__ koff,
                           float* __restrict__ part) {
    int b = blockIdx.x, ch = blockIdx.y;      // 32 chunks of 64 rows
    int d = threadIdx.x;                      // 256 threads -> 2 cols each
    int base = koff[b*8] + ch * 64;
    float a0 = 0.f, a1 = 0.f;
    for (int t = 0; t < 64; ++t) {
        const ushort* row = Kc + (size_t)(base + t) * DD;
        a0 += b2f(row[d]); a1 += b2f(row[d + 256]);
    }
    part[((size_t)(b*32 + ch))*DD + d]       = a0;
    part[((size_t)(b*32 + ch))*DD + d + 256] = a1;
}
__global__ void k_meanfinal(const float* __restrict__ part, float* __restrict__ meanV) {
    int b = blockIdx.x; int d = threadIdx.x;  // 512 threads
    float a0 = 0.f;
    for (int ch = 0; ch < 32; ++ch)
        a0 += part[((size_t)(b*32 + ch))*DD + d];
    meanV[b*DD + d] = a0 * (1.0f/SKL);
}

// ---------------- grouped scores S = Qc @ Kc^T (scale pre-folded into Qc) ----------------
__global__ __launch_bounds__(256) void k_scores_mfma(
        const ushort* __restrict__ Qc, const ushort* __restrict__ Kc,
        const int* __restrict__ qcnt, const int* __restrict__ kcnt,
        const int* __restrict__ qoff, const int* __restrict__ koff,
        const int* __restrict__ soff, const int* __restrict__ counts,
        const int* __restrict__ scl, float* __restrict__ S) {
    int tid = threadIdx.x, wid = tid >> 6, lane = tid & 63;
    int wr = wid >> 1, wc = wid & 1;
    int lr = lane & 15, lk = (lane >> 4) * 8;
    int cnt = counts[1];
    int vbid = (blockIdx.x & 7) * 128 + (blockIdx.x >> 3);  // XCD-chunked (1024 blocks)
    for (int slot = vbid; slot < cnt; slot += gridDim.x) {
        int e = scl[slot];
        int g = (e >> 10) & 31, qt = ((e >> 5) & 31) * 64, kt = (e & 31) * 64;
        int nq = qcnt[g], nk = kcnt[g];
        int qb = qoff[g], kb = koff[g];

        const ushort* ap[2];
#pragma unroll
        for (int t = 0; t < 2; ++t)
            ap[t] = Qc + (size_t)(qb + min(qt + wr*32 + t*16 + lr, nq - 1)) * DD + lk;
        const ushort* bp[2];
#pragma unroll
        for (int c = 0; c < 2; ++c)
            bp[c] = Kc + (size_t)(kb + min(kt + wc*32 + c*16 + lr, nk - 1)) * DD + lk;

        f32x4 acc[2][2];
#pragma unroll
        for (int t = 0; t < 2; ++t)
#pragma unroll
            for (int c = 0; c < 2; ++c) acc[t][c] = (f32x4){0.f, 0.f, 0.f, 0.f};

        short8v a[2], bb[2], an[2], bn[2];
#pragma unroll
        for (int t = 0; t < 2; ++t) a[t]  = *(const short8v*)(ap[t]);
#pragma unroll
        for (int c = 0; c < 2; ++c) bb[c] = *(const short8v*)(bp[c]);
        for (int d0 = 0; d0 < DD; d0 += 32) {
            int dn = d0 + 32;
            if (dn < DD) {
#pragma unroll
                for (int t = 0; t < 2; ++t) an[t] = *(const short8v*)(ap[t] + dn);
#pragma unroll
                for (int c = 0; c < 2; ++c) bn[c] = *(const short8v*)(bp[c] + dn);
            }
#pragma unroll
            for (int t = 0; t < 2; ++t)
#pragma unroll
                for (int c = 0; c < 2; ++c)
                    acc[t][c] = __builtin_amdgcn_mfma_f32_16x16x32_bf16(a[t], bb[c], acc[t][c], 0, 0, 0);
#pragma unroll
            for (int t = 0; t < 2; ++t) a[t] = an[t];
#pragma unroll
            for (int c = 0; c < 2; ++c) bb[c] = bn[c];
        }

        int sbase = soff[g];
        int rb = (lane >> 4) << 2;
#pragma unroll
        for (int t = 0; t < 2; ++t) {
#pragma unroll
            for (int r = 0; r < 4; ++r) {
                int gr = qt + wr*32 + t*16 + rb + r;
                if (gr >= nq) continue;
#pragma unroll
                for (int c = 0; c < 2; ++c) {
                    int gc = kt + wc*32 + c*16 + lr;
                    if (gc < nk) S[(size_t)sbase + (size_t)gr*nk + gc] = acc[t][c][r];
                }
            }
        }
    }
}

// ---------------- softmax rows -> bf16 probs, zero-padded to nk64, skewed stride ----------------
__global__ void k_softmax(const int* __restrict__ qcnt, const int* __restrict__ kcnt,
                          const int* __restrict__ soff, const int* __restrict__ pboff,
                          float* __restrict__ S, ushort* __restrict__ Pb) {
    int g = blockIdx.x;
    int nq = qcnt[g], nk = kcnt[g];
    if (nk == 0) return;
    int wid = threadIdx.x >> 6, lane = threadIdx.x & 63;
    int nk64 = (nk + 63) & ~63;
    int nks = nk64 + 32;
    for (int row = blockIdx.y * 16 + wid; row < nq; row += 512) {
        float* p = S + (size_t)soff[g] + (size_t)row * nk;
        ushort* pr = Pb + (size_t)pboff[g] + (size_t)row * nks;
        float mx = -3.4e38f;
        for (int c = lane; c < nk; c += 64) mx = fmaxf(mx, p[c]);
#pragma unroll
        for (int off = 32; off > 0; off >>= 1) mx = fmaxf(mx, __shfl_xor(mx, off));
        float sm = 0.f;
        for (int c = lane; c < nk; c += 64) { float e = __expf(p[c] - mx); p[c] = e; sm += e; }
#pragma unroll
        for (int off = 32; off > 0; off >>= 1) sm += __shfl_xor(sm, off);
        float inv = 1.0f / sm;
        for (int c = lane; c < nk64; c += 64) {
            float v = (c < nk) ? p[c] * inv : 0.f;
            pr[c] = f2b(v);
        }
    }
}

// ---------------- PV: O = P @ Kc via KcT, LDS-staged bf16 MFMA, epilogue += Q ----------------
// Per 64-key step: coalesced gload16 stages P(32x64) + KcT(128x64) into dbuf LDS
// (linear dest, pre-swizzled source col); swizzled ds_read_b128 fragments; 8 MFMA/wave.
__global__ __launch_bounds__(256) void k_pv_mfma(
        const ushort* __restrict__ Pb, const ushort* __restrict__ KcT,
        const float* __restrict__ Q,
        const int* __restrict__ qcnt, const int* __restrict__ kcnt,
        const int* __restrict__ tkoff, const int* __restrict__ pboff,
        const int* __restrict__ qlist, const int* __restrict__ counts,
        const int* __restrict__ pvl, float* __restrict__ out) {
    __shared__ ushort plds[2][2048];          // 32 rows x 64 keys
    __shared__ ushort klds[2][8192];          // 128 cols x 64 keys
    int tid = threadIdx.x, wid = tid >> 6, lane = tid & 63;
    int lr = lane & 15;
    int h  = lane >> 4;
    int x7 = lr & 7;
    int csz0 = ((h ^ x7) << 3);
    int csz1 = (((4 | h) ^ x7) << 3);
    int e8 = lane >> 3;                       // row-within-chunk (0..7)
    int glcs = (((lane & 7) ^ e8) << 3);      // pre-swizzled source col (ushorts)
    int cnt = counts[2];
    int vbid = (blockIdx.x & 7) * 32 + (blockIdx.x >> 3);   // XCD-chunked (256 blocks)
    int dt = blockIdx.y * 128;

    for (int slot = vbid; slot < cnt; slot += gridDim.x) {
        int e = pvl[slot];
        int g = e >> 7, qt = (e & 127) * 32;
        int nq = qcnt[g], nk = kcnt[g];
        int b = g >> 3;
        int nk64 = (nk + 63) & ~63;
        int nks = nk64 + 32;
        int tk = tkoff[g], pbase = pboff[g];

        const ushort* psrc = Pb + (size_t)pbase
            + (size_t)min(qt + wid*8 + e8, nq - 1) * nks + glcs;
        const ushort* ksrc[4];
#pragma unroll
        for (int p = 0; p < 4; ++p) {
            int col = (wid + p*4) * 8 + e8;   // 0..127
            ksrc[p] = KcT + (size_t)tk + (size_t)(dt + col) * nks + glcs;
        }

        auto STAGE = [&](int buf, int kt) {
            int k0 = kt * 64;
            gload16(psrc + k0, &plds[buf][wid * 512]);
#pragma unroll
            for (int p = 0; p < 4; ++p)
                gload16(ksrc[p] + k0, &klds[buf][(wid + p*4) * 512]);
        };

        f32x4 acc[2][2];
#pragma unroll
        for (int t = 0; t < 2; ++t)
#pragma unroll
            for (int c = 0; c < 2; ++c) acc[t][c] = (f32x4){0.f, 0.f, 0.f, 0.f};

        int nt = nk64 >> 6;
        __syncthreads();                      // prev slot done with LDS
        STAGE(0, 0);
        __syncthreads();
        for (int kt = 0; kt < nt; ++kt) {
            int cur = kt & 1;
            if (kt + 1 < nt) STAGE(cur ^ 1, kt + 1);
            const ushort* P_ = plds[cur];
            const ushort* K_ = klds[cur];
#pragma unroll
            for (int kk = 0; kk < 2; ++kk) {
                int csz = kk ? csz1 : csz0;
                short8v a[2], bb[2];
#pragma unroll
                for (int t = 0; t < 2; ++t)
                    a[t] = *(const short8v*)(P_ + (t*16 + lr)*64 + csz);
#pragma unroll
                for (int c = 0; c < 2; ++c)
                    bb[c] = *(const short8v*)(K_ + (wid*32 + c*16 + lr)*64 + csz);
#pragma unroll
                for (int t = 0; t < 2; ++t)
#pragma unroll
                    for (int c = 0; c < 2; ++c)
                        acc[t][c] = __builtin_amdgcn_mfma_f32_16x16x32_bf16(a[t], bb[c], acc[t][c], 0, 0, 0);
            }
            __syncthreads();                  // prefetch drained; buf swap safe
        }

        int rb = (lane >> 4) << 2;
#pragma unroll
        for (int t = 0; t < 2; ++t) {
#pragma unroll
            for (int r = 0; r < 4; ++r) {
                int gr = qt + t*16 + rb + r;
                if (gr >= nq) continue;
                int qrow = qlist[g*SQL + gr];
                size_t obase = ((size_t)(b*SQL) + qrow) * DD;
#pragma unroll
                for (int c = 0; c < 2; ++c) {
                    size_t o = obase + dt + wid*32 + c*16 + lr;
                    out[o] = acc[t][c][r] + Q[o];
                }
            }
        }
    }
}

// ---------------- fallback for groups with no keys: O = mean(Kp) + Q ----------------
__global__ void k_fallback(const float* __restrict__ Q, const float* __restrict__ meanV,
                           const int* __restrict__ qcnt, const int* __restrict__ kcnt,
                           const int* __restrict__ qlist, float* __restrict__ out) {
    int g = blockIdx.x;
    if (kcnt[g] != 0) return;
    int nq = qcnt[g]; int b = g >> 3;
    int r0 = blockIdx.y * 256;
    int rend = min(r0 + 256, nq);
    for (int r = r0; r < rend; ++r) {
        int qrow = qlist[g*SQL + r];
        size_t base = ((size_t)(b*SQL) + qrow) * DD;
        for (int d = threadIdx.x; d < DD; d += 256)
            out[base + d] = meanV[b*DD + d] + Q[base + d];
    }
}

extern "C" void kernel_launch(void* const* d_in, const int* in_sizes, int n_in,
                              void* d_out, int out_size, void* d_ws, size_t ws_size,
                              hipStream_t stream) {
    (void)in_sizes; (void)n_in; (void)out_size; (void)ws_size;
    const float* Q   = (const float*)d_in[0];
    const float* K   = (const float*)d_in[1];
    // d_in[2] (V) unused: Vp == Kp in the reference.
    const float* miu = (const float*)d_in[3];
    const float* Wq  = (const float*)d_in[4];
    const float* bq  = (const float*)d_in[5];
    const float* Wk  = (const float*)d_in[6];
    const float* bk  = (const float*)d_in[7];
    float* out = (float*)d_out;
    char* ws = (char*)d_ws;

    size_t off = 0;
    auto alloc = [&](size_t bytes) { size_t o = off; off += (bytes + 255) & ~(size_t)255; return o; };
    int*   aq     = (int*)  (ws + alloc((size_t)BB*SQL*4));
    int*   ak     = (int*)  (ws + alloc((size_t)BB*SKL*4));
    int*   qcnt   = (int*)  (ws + alloc(NG*4));
    int*   kcnt   = (int*)  (ws + alloc(NG*4));
    int*   soff   = (int*)  (ws + alloc((NG+1)*4));
    int*   pboff  = (int*)  (ws + alloc((NG+1)*4));
    int*   qoff   = (int*)  (ws + alloc((NG+1)*4));
    int*   koff   = (int*)  (ws + alloc((NG+1)*4));
    int*   tkoff  = (int*)  (ws + alloc((NG+1)*4));
    int*   counts = (int*)  (ws + alloc(16*4));
    int*   projl  = (int*)  (ws + alloc(PROJCAP*4));
    int*   scl    = (int*)  (ws + alloc(SCCAP*4));
    int*   pvl    = (int*)  (ws + alloc(PVCAP*4));
    int*   qlist  = (int*)  (ws + alloc((size_t)NG*SQL*4));
    int*   klist  = (int*)  (ws + alloc((size_t)NG*SKL*4));
    float* part   = (float*)(ws + alloc((size_t)BB*32*DD*4));
    float* meanV  = (float*)(ws + alloc((size_t)BB*DD*4));
    ushort* Qc    = (ushort*)(ws + alloc((size_t)BB*SQL*DD*2));
    ushort* Kc    = (ushort*)(ws + alloc((size_t)BB*SKL*DD*2));
    ushort* KcT   = (ushort*)(ws + alloc(KTCAP*2));
    ushort* Pb    = (ushort*)(ws + alloc((size_t)PCAP*2));
    // Union region (34 MB): bf16 staging Wqt|Wkt|Qb16|Kb16 (dead after proj), then S (f32).
    size_t uoff = alloc((size_t)UCAP);
    float* S     = (float*)(ws + uoff);
    ushort* Wqt  = (ushort*)(ws + uoff);
    ushort* Wkt  = Wqt  + (size_t)MM*DD*DD;
    ushort* Qb16 = Wkt  + (size_t)MM*DD*DD;
    ushort* Kb16 = Qb16 + (size_t)BB*SQL*DD;

    k_route     <<<NTOK/4, 256, 0, stream>>>(Q, K, miu, aq, ak, Qb16, Kb16);
    k_compact   <<<NG*2, 64, 0, stream>>>(aq, ak, qcnt, kcnt, qlist, klist);
    k_soff      <<<1, 64, 0, stream>>>(qcnt, kcnt, soff, pboff, qoff, koff, tkoff,
                                       counts, projl, scl, pvl);
    k_cvtW      <<<dim3(16, 16, 16), dim3(32, 8), 0, stream>>>(Wq, Wk, Wqt, Wkt);
    k_proj_mfma <<<dim3(192, 4), 256, 0, stream>>>(Qb16, Kb16, Wqt, Wkt, bq, bk,
                                                   qcnt, kcnt, qlist, klist, qoff, koff,
                                                   tkoff, counts, projl, Qc, Kc, KcT);
    k_meanpart  <<<dim3(BB, 32), 256, 0, stream>>>(Kc, koff, part);
    k_meanfinal <<<BB, 512, 0, stream>>>(part, meanV);
    k_scores_mfma<<<1024, 256, 0, stream>>>(Qc, Kc, qcnt, kcnt, qoff, koff, soff,
                                            counts, scl, S);
    k_softmax   <<<dim3(NG, 32), 1024, 0, stream>>>(qcnt, kcnt, soff, pboff, S, Pb);
    k_pv_mfma   <<<dim3(256, 4), 256, 0, stream>>>(Pb, KcT, Q, qcnt, kcnt, tkoff, pboff,
                                                   qlist, counts, pvl, out);
    k_fallback  <<<dim3(NG, 8), 256, 0, stream>>>(Q, meanV, qcnt, kcnt, qlist, out);
}

// Round 20
// 142.428 us; speedup vs baseline: 1.2243x; 1.1499x over previous
//
#include <hip/hip_runtime.h>
#include <hip/hip_bf16.h>
#include <math.h>

#define BB  4
#define SQL 2048
#define SKL 2048
#define DD  512
#define MM  8
#define NG  (BB*MM)
#define NTOK (BB*(SQL+SKL))
#define PCAP (8u*1024u*1024u)    // bf16 prob scratch cap (elements)
#define KTCAP ((size_t)DD*11264) // bf16 KcT cap (elements), 64-aligned+skewed rows
#define UCAP  (34u*1024u*1024u)  // union region bytes: S (f32) | Wqt|Wkt|Qb16|Kb16
#define PROJCAP 512
#define SCCAP   6144
#define PVCAP   512
#define SCALE 0.04419417382415922f

typedef __attribute__((ext_vector_type(8))) short short8v;
typedef __attribute__((ext_vector_type(4))) float f32x4;

__device__ __forceinline__ ushort f2b(float x) {
    union { __hip_bfloat16 h; ushort u; } cv; cv.h = __float2bfloat16(x); return cv.u;
}
__device__ __forceinline__ float b2f(ushort x) {
    union { ushort u; __hip_bfloat16 h; } cv; cv.u = x; return __bfloat162float(cv.h);
}
// tanh-form GELU: x*e/(e+1), e = exp(2*sqrt(2/pi)*(x + 0.044715 x^3)).
__device__ __forceinline__ float gelu_fast(float x) {
    float z2 = 1.5957691216057308f * x * (1.0f + 0.044715f * x * x);
    float e = __expf(fminf(z2, 40.0f));
    return x * e * __builtin_amdgcn_rcpf(e + 1.0f);
}
__device__ __forceinline__ void gload16(const ushort* g, ushort* l) {
    __builtin_amdgcn_global_load_lds(
        (const __attribute__((address_space(1))) void*)g,
        (__attribute__((address_space(3))) void*)l, 16, 0, 0);
}

// ---------------- routing: f64 accum argmax; also emits bf16 token-order Q/K ----------------
__global__ void k_route(const float* __restrict__ Q, const float* __restrict__ K,
                        const float* __restrict__ miu,
                        int* __restrict__ aq, int* __restrict__ ak,
                        ushort* __restrict__ Qb16, ushort* __restrict__ Kb16) {
    int g    = blockIdx.x * 4 + (threadIdx.x >> 6);
    int lane = threadIdx.x & 63;
    int b = g >> 12;
    int t = g & 4095;
    bool isQ = (t < SQL);
    size_t rowoff = isQ ? (size_t)(b*SQL + t) * DD : (size_t)(b*SKL + (t - SQL)) * DD;
    const float* x = (isQ ? Q : K) + rowoff;
    ushort* yb = (isQ ? Qb16 : Kb16) + rowoff;
    double acc[MM];
#pragma unroll
    for (int m = 0; m < MM; ++m) acc[m] = 0.0;
#pragma unroll
    for (int j = 0; j < 8; ++j) {
        int i = j * 64 + lane;
        float xv = x[i];
        yb[i] = f2b(xv);
#pragma unroll
        for (int m = 0; m < MM; ++m) acc[m] += (double)xv * (double)miu[m*DD + i];
    }
#pragma unroll
    for (int m = 0; m < MM; ++m) {
#pragma unroll
        for (int off = 32; off > 0; off >>= 1)
            acc[m] += __shfl_down(acc[m], off);
    }
    if (lane == 0) {
        double best = acc[0]; int bi = 0;
#pragma unroll
        for (int m = 1; m < MM; ++m) if (acc[m] > best) { best = acc[m]; bi = m; }
        if (isQ) aq[b*SQL + t] = bi; else ak[b*SKL + (t - SQL)] = bi;
    }
}

// ---------------- stable compaction into per-(b,m) index lists ----------------
__global__ void k_compact(const int* __restrict__ aq, const int* __restrict__ ak,
                          int* __restrict__ qcnt, int* __restrict__ kcnt,
                          int* __restrict__ qlist, int* __restrict__ klist) {
    int idx = blockIdx.x;
    int isK = idx >> 5;
    int g   = idx & 31;
    int b = g >> 3, m = g & 7;
    const int* a = isK ? (ak + b*SKL) : (aq + b*SQL);
    int* list = (isK ? klist : qlist) + g*SQL;
    int lane = threadIdx.x;
    int base = 0;
    for (int c = 0; c < SQL; c += 64) {
        int s = c + lane;
        bool f = (a[s] == m);
        unsigned long long mk = __ballot(f);
        int before = __popcll(mk & ((1ull << lane) - 1ull));
        if (f) list[base + before] = s;
        base += __popcll(mk);
    }
    if (lane == 0) (isK ? kcnt : qcnt)[g] = base;
}

// ---------------- offsets + compact tile work-lists ----------------
__global__ void k_soff(const int* __restrict__ qcnt, const int* __restrict__ kcnt,
                       int* __restrict__ soff, int* __restrict__ pboff,
                       int* __restrict__ qoff, int* __restrict__ koff,
                       int* __restrict__ tkoff, int* __restrict__ counts,
                       int* __restrict__ projl, int* __restrict__ scl,
                       int* __restrict__ pvl) {
    __shared__ int pbase[64], sbase[32], pvbase[32];
    int lane = threadIdx.x;
    if (lane == 0) {
        int sacc = 0, pacc = 0, qa = 0, ka = 0, ta = 0;
        for (int g = 0; g < NG; ++g) {
            soff[g] = sacc; pboff[g] = pacc; qoff[g] = qa; koff[g] = ka; tkoff[g] = ta;
            int nq = qcnt[g], nk = kcnt[g];
            int nks = ((nk + 63) & ~63) + 32;
            sacc += nq * nk; pacc += nq * nks; qa += nq; ka += nk; ta += DD * nks;
        }
        soff[NG] = sacc; pboff[NG] = pacc; qoff[NG] = qa; koff[NG] = ka; tkoff[NG] = ta;
        int pj = 0, sc = 0, pv = 0;
        for (int sg = 0; sg < 64; ++sg) {
            int n = (sg >= 32 ? kcnt : qcnt)[sg & 31];
            pbase[sg] = pj; pj += (n + 127) >> 7;     // 128-token proj tiles
        }
        for (int g = 0; g < NG; ++g) {
            int nq = qcnt[g], nk = kcnt[g];
            sbase[g] = sc; pvbase[g] = pv;
            if (nq > 0 && nk > 0) {
                sc += ((nq + 63) >> 6) * ((nk + 63) >> 6);
                pv += (nq + 31) >> 5;                 // 32-row pv tiles
            }
        }
        counts[0] = pj; counts[1] = sc; counts[2] = pv;
    }
    __syncthreads();
    {   // proj tiles: one (side,g) per lane
        int sg = lane;
        int side = sg >> 5, g = sg & 31;
        int n = (side ? kcnt : qcnt)[g];
        int ntile = (n + 127) >> 7;
        int base = pbase[sg];
        for (int ty = 0; ty < ntile; ++ty)
            projl[base + ty] = (side << 11) | (g << 6) | ty;
    }
    if (lane < 32) {   // scores + pv tiles: one g per lane (group-contiguous order)
        int g = lane;
        int nq = qcnt[g], nk = kcnt[g];
        if (nq > 0 && nk > 0) {
            int nqt = (nq + 63) >> 6, nkt = (nk + 63) >> 6;
            int idx = sbase[g];
            for (int qy = 0; qy < nqt; ++qy)
                for (int ky = 0; ky < nkt; ++ky)
                    scl[idx++] = (g << 10) | (qy << 5) | ky;
            int nqt32 = (nq + 31) >> 5;
            int pidx = pvbase[g];
            for (int qy = 0; qy < nqt32; ++qy)
                pvl[pidx++] = (g << 7) | qy;          // qy fits 7 bits (<= 64)
        }
    }
}

// W[m][d][e] (f32) -> Wt[m][e][d] (bf16), tiled transpose
__global__ void k_cvtW(const float* __restrict__ Wq, const float* __restrict__ Wk,
                       ushort* __restrict__ Wqt, ushort* __restrict__ Wkt) {
    __shared__ float tile[32][33];
    int mm = blockIdx.x; int isK = mm >> 3; int m = mm & 7;
    const float* W = (isK ? Wk : Wq) + (size_t)m * DD * DD;
    ushort* Wt = (isK ? Wkt : Wqt) + (size_t)m * DD * DD;
    int d0 = blockIdx.y * 32, e0 = blockIdx.z * 32;
    int tx = threadIdx.x, ty = threadIdx.y;   // 32 x 8
    for (int i = ty; i < 32; i += 8)
        tile[i][tx] = W[(size_t)(d0 + i) * DD + e0 + tx];
    __syncthreads();
    for (int i = ty; i < 32; i += 8)
        Wt[(size_t)(e0 + i) * DD + d0 + tx] = f2b(tile[tx][i]);
}

// ---------------- grouped expert projection: 2-phase dbuf + XOR-swizzled LDS ----------------
__global__ __launch_bounds__(256) void k_proj_mfma(
        const ushort* __restrict__ Qb16, const ushort* __restrict__ Kb16,
        const ushort* __restrict__ Wqt, const ushort* __restrict__ Wkt,
        const float* __restrict__ bq, const float* __restrict__ bk,
        const int* __restrict__ qcnt, const int* __restrict__ kcnt,
        const int* __restrict__ qlist, const int* __restrict__ klist,
        const int* __restrict__ qoff, const int* __restrict__ koff,
        const int* __restrict__ tkoff, const int* __restrict__ counts,
        const int* __restrict__ projl,
        ushort* __restrict__ Qc, ushort* __restrict__ Kc, ushort* __restrict__ KcT) {
    __shared__ ushort lds[2][16384];          // per buf: As[128][64] | Bs[128][64]
    __shared__ int rows[128];
    int tid = threadIdx.x;
    int wid = tid >> 6, lane = tid & 63;
    int wr = wid >> 1, wc = wid & 1;
    int lr = lane & 15;
    int h = lane >> 4;                        // 0..3 (k-slot)
    int x7 = lr & 7;                          // read-side swizzle key
    int csz0 = ((h ^ x7) << 3);               // swizzled read col (ushorts), kk=0
    int csz1 = (((4 | h) ^ x7) << 3);         // kk=1
    int c0 = blockIdx.y * 128;
    int e8 = lane >> 3;                       // stage: row-within-chunk
    int glcs = (((lane & 7) ^ e8) << 3);      // stage: PRE-SWIZZLED source col (ushorts)
    int cnt = counts[0];
    int vbid = (blockIdx.x & 7) * 24 + (blockIdx.x >> 3);   // XCD-chunked (192 blocks)

    for (int slot = vbid; slot < cnt; slot += gridDim.x) {
        int e = projl[slot];
        int isK = (e >> 11) & 1, g = (e >> 6) & 31, ty = e & 63;
        int n = (isK ? kcnt : qcnt)[g];
        int obase = (isK ? koff : qoff)[g];
        int b = g >> 3, m = g & 7;
        const ushort* Xtok = (isK ? Kb16 : Qb16) + (size_t)b * SQL * DD;
        const ushort* Wt = (isK ? Wkt : Wqt) + (size_t)m * DD * DD;
        const float* bias = (isK ? bk : bq) + m * DD;
        const int* list = (isK ? klist : qlist) + g * SQL;
        int t0 = ty * 128;

        __syncthreads();                      // prev slot done with rows[]
        if (tid < 128) rows[tid] = list[min(t0 + tid, n - 1)];
        __syncthreads();

        auto STAGE = [&](int buf, int kt) {
            int d0 = kt * 64;
            ushort* As = lds[buf];
            ushort* Bs = lds[buf] + 8192;
#pragma unroll
            for (int j0 = 0; j0 < 4; ++j0) {
                int j = wid + j0 * 4;         // chunk 0..15 (8 rows each)
                int rtok = rows[j*8 + e8];
                gload16(Xtok + (size_t)rtok * DD + d0 + glcs, As + j*512);
                int rB = c0 + j*8 + e8;
                gload16(Wt + (size_t)rB * DD + d0 + glcs, Bs + j*512);
            }
        };

        f32x4 acc[4][4];
#pragma unroll
        for (int t = 0; t < 4; ++t)
#pragma unroll
            for (int c = 0; c < 4; ++c) acc[t][c] = (f32x4){0.f, 0.f, 0.f, 0.f};

        STAGE(0, 0);
        __syncthreads();
        for (int kt = 0; kt < 8; ++kt) {
            int cur = kt & 1;
            if (kt < 7) STAGE(cur ^ 1, kt + 1);   // prefetch next K-step (overlaps MFMA)
            const ushort* As = lds[cur];
            const ushort* Bs = lds[cur] + 8192;
#pragma unroll
            for (int kk = 0; kk < 2; ++kk) {
                int csz = kk ? csz1 : csz0;
                short8v a[4], bb[4];
#pragma unroll
                for (int t = 0; t < 4; ++t)
                    a[t] = *(const short8v*)(As + (wr*64 + t*16 + lr)*64 + csz);
#pragma unroll
                for (int c = 0; c < 4; ++c)
                    bb[c] = *(const short8v*)(Bs + (wc*64 + c*16 + lr)*64 + csz);
#pragma unroll
                for (int t = 0; t < 4; ++t)
#pragma unroll
                    for (int c = 0; c < 4; ++c)
                        acc[t][c] = __builtin_amdgcn_mfma_f32_16x16x32_bf16(a[t], bb[c], acc[t][c], 0, 0, 0);
            }
            __syncthreads();                  // drains prefetch vmcnt; buf swap safe
        }

        float bcache[4];
#pragma unroll
        for (int c = 0; c < 4; ++c) bcache[c] = bias[c0 + wc*64 + c*16 + lr];

        int rb = (lane >> 4) << 2;
        int nk2 = kcnt[g];
        int nks = ((nk2 + 63) & ~63) + 32;    // 64-aligned + skewed KcT row stride
        int tk = tkoff[g];
        ushort* Yc = isK ? Kc : Qc;
#pragma unroll
        for (int t = 0; t < 4; ++t) {
            int grow = ty*128 + wr*64 + t*16 + rb;   // group-relative row of r=0
#pragma unroll
            for (int c = 0; c < 4; ++c) {
                int col = c0 + wc*64 + c*16 + lr;
                float v[4];
#pragma unroll
                for (int r = 0; r < 4; ++r) v[r] = gelu_fast(acc[t][c][r] + bcache[c]);
                if (!isK) {
#pragma unroll
                    for (int r = 0; r < 4; ++r)
                        if (grow + r < n)
                            Yc[(size_t)(obase + grow + r) * DD + col] = f2b(v[r] * SCALE);
                } else {
#pragma unroll
                    for (int r = 0; r < 4; ++r)
                        if (grow + r < n)
                            Yc[(size_t)(obase + grow + r) * DD + col] = f2b(v[r]);
                    size_t taddr = (size_t)tk + (size_t)col * nks + grow;
                    if (grow + 3 < n) {
                        ushort4 o; o.x = f2b(v[0]); o.y = f2b(v[1]); o.z = f2b(v[2]); o.w = f2b(v[3]);
                        *(ushort4*)(KcT + taddr) = o;
                    } else {
#pragma unroll
                        for (int r = 0; r < 4; ++r)
                            if (grow + r < n) KcT[taddr + r] = f2b(v[r]);
                    }
                }
            }
        }
    }
}

// ---------------- mean of Kp over all keys (fallback value), two-stage ----------------
__global__ void k_meanpart(const ushort* __restrict__ Kc, const int* __restrict__ koff,
                           float* __restrict__ part) {
    int b = blockIdx.x, ch = blockIdx.y;      // 32 chunks of 64 rows
    int d = threadIdx.x;                      // 256 threads -> 2 cols each
    int base = koff[b*8] + ch * 64;
    float a0 = 0.f, a1 = 0.f;
    for (int t = 0; t < 64; ++t) {
        const ushort* row = Kc + (size_t)(base + t) * DD;
        a0 += b2f(row[d]); a1 += b2f(row[d + 256]);
    }
    part[((size_t)(b*32 + ch))*DD + d]       = a0;
    part[((size_t)(b*32 + ch))*DD + d + 256] = a1;
}
__global__ void k_meanfinal(const float* __restrict__ part, float* __restrict__ meanV) {
    int b = blockIdx.x; int d = threadIdx.x;  // 512 threads
    float a0 = 0.f;
    for (int ch = 0; ch < 32; ++ch)
        a0 += part[((size_t)(b*32 + ch))*DD + d];
    meanV[b*DD + d] = a0 * (1.0f/SKL);
}

// ---------------- grouped scores S = Qc @ Kc^T: LDS-staged (TA-coalesced) ----------------
// Per 64-d step: stage Qc(64x64) + Kc(64x64) via coalesced 8-row x 128B gload16
// (linear dest + pre-swizzled source col); swizzled ds_read_b128 fragments.
// Replaces 16-cache-line strided fragment gathers (PV's proven pathology).
__global__ __launch_bounds__(256) void k_scores_mfma(
        const ushort* __restrict__ Qc, const ushort* __restrict__ Kc,
        const int* __restrict__ qcnt, const int* __restrict__ kcnt,
        const int* __restrict__ qoff, const int* __restrict__ koff,
        const int* __restrict__ soff, const int* __restrict__ counts,
        const int* __restrict__ scl, float* __restrict__ S) {
    __shared__ ushort lds[2][8192];           // per buf: As[64][64] | Bs[64][64]
    int tid = threadIdx.x, wid = tid >> 6, lane = tid & 63;
    int wr = wid >> 1, wc = wid & 1;
    int lr = lane & 15;
    int h  = lane >> 4;
    int x7 = lr & 7;
    int csz0 = ((h ^ x7) << 3);
    int csz1 = (((4 | h) ^ x7) << 3);
    int e8 = lane >> 3;                       // row-within-chunk (0..7)
    int glcs = (((lane & 7) ^ e8) << 3);      // pre-swizzled source col (ushorts)
    int cnt = counts[1];
    int vbid = (blockIdx.x & 7) * 128 + (blockIdx.x >> 3);  // XCD-chunked (1024 blocks)
    for (int slot = vbid; slot < cnt; slot += gridDim.x) {
        int e = scl[slot];
        int g = (e >> 10) & 31, qt = ((e >> 5) & 31) * 64, kt = (e & 31) * 64;
        int nq = qcnt[g], nk = kcnt[g];
        int qb = qoff[g], kb = koff[g];

        auto STAGE = [&](int buf, int dstep) {
            int d0 = dstep * 64;
            ushort* As = lds[buf];
            ushort* Bs = lds[buf] + 4096;
#pragma unroll
            for (int j0 = 0; j0 < 4; ++j0) {
                int j = wid + j0 * 4;         // 0..15: A chunks 0-7, B chunks 8-15
                if (j < 8) {
                    int r = qb + min(qt + j*8 + e8, nq - 1);
                    gload16(Qc + (size_t)r * DD + d0 + glcs, As + j*512);
                } else {
                    int jb = j - 8;
                    int r = kb + min(kt + jb*8 + e8, nk - 1);
                    gload16(Kc + (size_t)r * DD + d0 + glcs, Bs + jb*512);
                }
            }
        };

        f32x4 acc[2][2];
#pragma unroll
        for (int t = 0; t < 2; ++t)
#pragma unroll
            for (int c = 0; c < 2; ++c) acc[t][c] = (f32x4){0.f, 0.f, 0.f, 0.f};

        __syncthreads();                      // prev slot done with LDS
        STAGE(0, 0);
        __syncthreads();
        for (int ds = 0; ds < 8; ++ds) {
            int cur = ds & 1;
            if (ds < 7) STAGE(cur ^ 1, ds + 1);   // prefetch next d-step
            const ushort* As = lds[cur];
            const ushort* Bs = lds[cur] + 4096;
#pragma unroll
            for (int kk = 0; kk < 2; ++kk) {
                int csz = kk ? csz1 : csz0;
                short8v a[2], bb[2];
#pragma unroll
                for (int t = 0; t < 2; ++t)
                    a[t] = *(const short8v*)(As + (wr*32 + t*16 + lr)*64 + csz);
#pragma unroll
                for (int c = 0; c < 2; ++c)
                    bb[c] = *(const short8v*)(Bs + (wc*32 + c*16 + lr)*64 + csz);
#pragma unroll
                for (int t = 0; t < 2; ++t)
#pragma unroll
                    for (int c = 0; c < 2; ++c)
                        acc[t][c] = __builtin_amdgcn_mfma_f32_16x16x32_bf16(a[t], bb[c], acc[t][c], 0, 0, 0);
            }
            __syncthreads();                  // prefetch drained; buf swap safe
        }

        int sbase = soff[g];
        int rb = (lane >> 4) << 2;
#pragma unroll
        for (int t = 0; t < 2; ++t) {
#pragma unroll
            for (int r = 0; r < 4; ++r) {
                int gr = qt + wr*32 + t*16 + rb + r;
                if (gr >= nq) continue;
#pragma unroll
                for (int c = 0; c < 2; ++c) {
                    int gc = kt + wc*32 + c*16 + lr;
                    if (gc < nk) S[(size_t)sbase + (size_t)gr*nk + gc] = acc[t][c][r];
                }
            }
        }
    }
}

// ---------------- softmax rows -> bf16 probs, zero-padded to nk64, skewed stride ----------------
__global__ void k_softmax(const int* __restrict__ qcnt, const int* __restrict__ kcnt,
                          const int* __restrict__ soff, const int* __restrict__ pboff,
                          float* __restrict__ S, ushort* __restrict__ Pb) {
    int g = blockIdx.x;
    int nq = qcnt[g], nk = kcnt[g];
    if (nk == 0) return;
    int wid = threadIdx.x >> 6, lane = threadIdx.x & 63;
    int nk64 = (nk + 63) & ~63;
    int nks = nk64 + 32;
    for (int row = blockIdx.y * 16 + wid; row < nq; row += 512) {
        float* p = S + (size_t)soff[g] + (size_t)row * nk;
        ushort* pr = Pb + (size_t)pboff[g] + (size_t)row * nks;
        float mx = -3.4e38f;
        for (int c = lane; c < nk; c += 64) mx = fmaxf(mx, p[c]);
#pragma unroll
        for (int off = 32; off > 0; off >>= 1) mx = fmaxf(mx, __shfl_xor(mx, off));
        float sm = 0.f;
        for (int c = lane; c < nk; c += 64) { float e = __expf(p[c] - mx); p[c] = e; sm += e; }
#pragma unroll
        for (int off = 32; off > 0; off >>= 1) sm += __shfl_xor(sm, off);
        float inv = 1.0f / sm;
        for (int c = lane; c < nk64; c += 64) {
            float v = (c < nk) ? p[c] * inv : 0.f;
            pr[c] = f2b(v);
        }
    }
}

// ---------------- PV: O = P @ Kc via KcT, LDS-staged bf16 MFMA, epilogue += Q ----------------
__global__ __launch_bounds__(256) void k_pv_mfma(
        const ushort* __restrict__ Pb, const ushort* __restrict__ KcT,
        const float* __restrict__ Q,
        const int* __restrict__ qcnt, const int* __restrict__ kcnt,
        const int* __restrict__ tkoff, const int* __restrict__ pboff,
        const int* __restrict__ qlist, const int* __restrict__ counts,
        const int* __restrict__ pvl, float* __restrict__ out) {
    __shared__ ushort plds[2][2048];          // 32 rows x 64 keys
    __shared__ ushort klds[2][8192];          // 128 cols x 64 keys
    int tid = threadIdx.x, wid = tid >> 6, lane = tid & 63;
    int lr = lane & 15;
    int h  = lane >> 4;
    int x7 = lr & 7;
    int csz0 = ((h ^ x7) << 3);
    int csz1 = (((4 | h) ^ x7) << 3);
    int e8 = lane >> 3;                       // row-within-chunk (0..7)
    int glcs = (((lane & 7) ^ e8) << 3);      // pre-swizzled source col (ushorts)
    int cnt = counts[2];
    int vbid = (blockIdx.x & 7) * 32 + (blockIdx.x >> 3);   // XCD-chunked (256 blocks)
    int dt = blockIdx.y * 128;

    for (int slot = vbid; slot < cnt; slot += gridDim.x) {
        int e = pvl[slot];
        int g = e >> 7, qt = (e & 127) * 32;
        int nq = qcnt[g], nk = kcnt[g];
        int b = g >> 3;
        int nk64 = (nk + 63) & ~63;
        int nks = nk64 + 32;
        int tk = tkoff[g], pbase = pboff[g];

        const ushort* psrc = Pb + (size_t)pbase
            + (size_t)min(qt + wid*8 + e8, nq - 1) * nks + glcs;
        const ushort* ksrc[4];
#pragma unroll
        for (int p = 0; p < 4; ++p) {
            int col = (wid + p*4) * 8 + e8;   // 0..127
            ksrc[p] = KcT + (size_t)tk + (size_t)(dt + col) * nks + glcs;
        }

        auto STAGE = [&](int buf, int kt) {
            int k0 = kt * 64;
            gload16(psrc + k0, &plds[buf][wid * 512]);
#pragma unroll
            for (int p = 0; p < 4; ++p)
                gload16(ksrc[p] + k0, &klds[buf][(wid + p*4) * 512]);
        };

        f32x4 acc[2][2];
#pragma unroll
        for (int t = 0; t < 2; ++t)
#pragma unroll
            for (int c = 0; c < 2; ++c) acc[t][c] = (f32x4){0.f, 0.f, 0.f, 0.f};

        int nt = nk64 >> 6;
        __syncthreads();                      // prev slot done with LDS
        STAGE(0, 0);
        __syncthreads();
        for (int kt = 0; kt < nt; ++kt) {
            int cur = kt & 1;
            if (kt + 1 < nt) STAGE(cur ^ 1, kt + 1);
            const ushort* P_ = plds[cur];
            const ushort* K_ = klds[cur];
#pragma unroll
            for (int kk = 0; kk < 2; ++kk) {
                int csz = kk ? csz1 : csz0;
                short8v a[2], bb[2];
#pragma unroll
                for (int t = 0; t < 2; ++t)
                    a[t] = *(const short8v*)(P_ + (t*16 + lr)*64 + csz);
#pragma unroll
                for (int c = 0; c < 2; ++c)
                    bb[c] = *(const short8v*)(K_ + (wid*32 + c*16 + lr)*64 + csz);
#pragma unroll
                for (int t = 0; t < 2; ++t)
#pragma unroll
                    for (int c = 0; c < 2; ++c)
                        acc[t][c] = __builtin_amdgcn_mfma_f32_16x16x32_bf16(a[t], bb[c], acc[t][c], 0, 0, 0);
            }
            __syncthreads();                  // prefetch drained; buf swap safe
        }

        int rb = (lane >> 4) << 2;
#pragma unroll
        for (int t = 0; t < 2; ++t) {
#pragma unroll
            for (int r = 0; r < 4; ++r) {
                int gr = qt + t*16 + rb + r;
                if (gr >= nq) continue;
                int qrow = qlist[g*SQL + gr];
                size_t obase = ((size_t)(b*SQL) + qrow) * DD;
#pragma unroll
                for (int c = 0; c < 2; ++c) {
                    size_t o = obase + dt + wid*32 + c*16 + lr;
                    out[o] = acc[t][c][r] + Q[o];
                }
            }
        }
    }
}

// ---------------- fallback for groups with no keys: O = mean(Kp) + Q ----------------
__global__ void k_fallback(const float* __restrict__ Q, const float* __restrict__ meanV,
                           const int* __restrict__ qcnt, const int* __restrict__ kcnt,
                           const int* __restrict__ qlist, float* __restrict__ out) {
    int g = blockIdx.x;
    if (kcnt[g] != 0) return;
    int nq = qcnt[g]; int b = g >> 3;
    int r0 = blockIdx.y * 256;
    int rend = min(r0 + 256, nq);
    for (int r = r0; r < rend; ++r) {
        int qrow = qlist[g*SQL + r];
        size_t base = ((size_t)(b*SQL) + qrow) * DD;
        for (int d = threadIdx.x; d < DD; d += 256)
            out[base + d] = meanV[b*DD + d] + Q[base + d];
    }
}

extern "C" void kernel_launch(void* const* d_in, const int* in_sizes, int n_in,
                              void* d_out, int out_size, void* d_ws, size_t ws_size,
                              hipStream_t stream) {
    (void)in_sizes; (void)n_in; (void)out_size; (void)ws_size;
    const float* Q   = (const float*)d_in[0];
    const float* K   = (const float*)d_in[1];
    // d_in[2] (V) unused: Vp == Kp in the reference.
    const float* miu = (const float*)d_in[3];
    const float* Wq  = (const float*)d_in[4];
    const float* bq  = (const float*)d_in[5];
    const float* Wk  = (const float*)d_in[6];
    const float* bk  = (const float*)d_in[7];
    float* out = (float*)d_out;
    char* ws = (char*)d_ws;

    size_t off = 0;
    auto alloc = [&](size_t bytes) { size_t o = off; off += (bytes + 255) & ~(size_t)255; return o; };
    int*   aq     = (int*)  (ws + alloc((size_t)BB*SQL*4));
    int*   ak     = (int*)  (ws + alloc((size_t)BB*SKL*4));
    int*   qcnt   = (int*)  (ws + alloc(NG*4));
    int*   kcnt   = (int*)  (ws + alloc(NG*4));
    int*   soff   = (int*)  (ws + alloc((NG+1)*4));
    int*   pboff  = (int*)  (ws + alloc((NG+1)*4));
    int*   qoff   = (int*)  (ws + alloc((NG+1)*4));
    int*   koff   = (int*)  (ws + alloc((NG+1)*4));
    int*   tkoff  = (int*)  (ws + alloc((NG+1)*4));
    int*   counts = (int*)  (ws + alloc(16*4));
    int*   projl  = (int*)  (ws + alloc(PROJCAP*4));
    int*   scl    = (int*)  (ws + alloc(SCCAP*4));
    int*   pvl    = (int*)  (ws + alloc(PVCAP*4));
    int*   qlist  = (int*)  (ws + alloc((size_t)NG*SQL*4));
    int*   klist  = (int*)  (ws + alloc((size_t)NG*SKL*4));
    float* part   = (float*)(ws + alloc((size_t)BB*32*DD*4));
    float* meanV  = (float*)(ws + alloc((size_t)BB*DD*4));
    ushort* Qc    = (ushort*)(ws + alloc((size_t)BB*SQL*DD*2));
    ushort* Kc    = (ushort*)(ws + alloc((size_t)BB*SKL*DD*2));
    ushort* KcT   = (ushort*)(ws + alloc(KTCAP*2));
    ushort* Pb    = (ushort*)(ws + alloc((size_t)PCAP*2));
    // Union region (34 MB): bf16 staging Wqt|Wkt|Qb16|Kb16 (dead after proj), then S (f32).
    size_t uoff = alloc((size_t)UCAP);
    float* S     = (float*)(ws + uoff);
    ushort* Wqt  = (ushort*)(ws + uoff);
    ushort* Wkt  = Wqt  + (size_t)MM*DD*DD;
    ushort* Qb16 = Wkt  + (size_t)MM*DD*DD;
    ushort* Kb16 = Qb16 + (size_t)BB*SQL*DD;

    k_route     <<<NTOK/4, 256, 0, stream>>>(Q, K, miu, aq, ak, Qb16, Kb16);
    k_compact   <<<NG*2, 64, 0, stream>>>(aq, ak, qcnt, kcnt, qlist, klist);
    k_soff      <<<1, 64, 0, stream>>>(qcnt, kcnt, soff, pboff, qoff, koff, tkoff,
                                       counts, projl, scl, pvl);
    k_cvtW      <<<dim3(16, 16, 16), dim3(32, 8), 0, stream>>>(Wq, Wk, Wqt, Wkt);
    k_proj_mfma <<<dim3(192, 4), 256, 0, stream>>>(Qb16, Kb16, Wqt, Wkt, bq, bk,
                                                   qcnt, kcnt, qlist, klist, qoff, koff,
                                                   tkoff, counts, projl, Qc, Kc, KcT);
    k_meanpart  <<<dim3(BB, 32), 256, 0, stream>>>(Kc, koff, part);
    k_meanfinal <<<BB, 512, 0, stream>>>(part, meanV);
    k_scores_mfma<<<1024, 256, 0, stream>>>(Qc, Kc, qcnt, kcnt, qoff, koff, soff,
                                            counts, scl, S);
    k_softmax   <<<dim3(NG, 32), 1024, 0, stream>>>(qcnt, kcnt, soff, pboff, S, Pb);
    k_pv_mfma   <<<dim3(256, 4), 256, 0, stream>>>(Pb, KcT, Q, qcnt, kcnt, tkoff, pboff,
                                                   qlist, counts, pvl, out);
    k_fallback  <<<dim3(NG, 8), 256, 0, stream>>>(Q, meanV, qcnt, kcnt, qlist, out);
}

// Round 21
// 141.386 us; speedup vs baseline: 1.2333x; 1.0074x over previous
//
#include <hip/hip_runtime.h>
#include <hip/hip_bf16.h>
#include <math.h>

#define BB  4
#define SQL 2048
#define SKL 2048
#define DD  512
#define MM  8
#define NG  (BB*MM)
#define NTOK (BB*(SQL+SKL))
#define PCAP (8u*1024u*1024u)    // bf16 prob scratch cap (elements)
#define KTCAP ((size_t)DD*11264) // bf16 KcT cap (elements), 64-aligned+skewed rows
#define UCAP  (34u*1024u*1024u)  // union region bytes: S (f32) | Wqt|Wkt|Qb16|Kb16
#define PROJCAP 512
#define SCCAP   6144
#define PVCAP   512
#define SCALE 0.04419417382415922f

typedef __attribute__((ext_vector_type(8))) short short8v;
typedef __attribute__((ext_vector_type(4))) float f32x4;

__device__ __forceinline__ ushort f2b(float x) {
    union { __hip_bfloat16 h; ushort u; } cv; cv.h = __float2bfloat16(x); return cv.u;
}
__device__ __forceinline__ float b2f(ushort x) {
    union { ushort u; __hip_bfloat16 h; } cv; cv.u = x; return __bfloat162float(cv.h);
}
// tanh-form GELU: x*e/(e+1), e = exp(2*sqrt(2/pi)*(x + 0.044715 x^3)).
__device__ __forceinline__ float gelu_fast(float x) {
    float z2 = 1.5957691216057308f * x * (1.0f + 0.044715f * x * x);
    float e = __expf(fminf(z2, 40.0f));
    return x * e * __builtin_amdgcn_rcpf(e + 1.0f);
}
__device__ __forceinline__ void gload16(const ushort* g, ushort* l) {
    __builtin_amdgcn_global_load_lds(
        (const __attribute__((address_space(1))) void*)g,
        (__attribute__((address_space(3))) void*)l, 16, 0, 0);
}

// ---------------- routing: f64 accum argmax; also emits bf16 token-order Q/K ----------------
__global__ void k_route(const float* __restrict__ Q, const float* __restrict__ K,
                        const float* __restrict__ miu,
                        int* __restrict__ aq, int* __restrict__ ak,
                        ushort* __restrict__ Qb16, ushort* __restrict__ Kb16) {
    int g    = blockIdx.x * 4 + (threadIdx.x >> 6);
    int lane = threadIdx.x & 63;
    int b = g >> 12;
    int t = g & 4095;
    bool isQ = (t < SQL);
    size_t rowoff = isQ ? (size_t)(b*SQL + t) * DD : (size_t)(b*SKL + (t - SQL)) * DD;
    const float* x = (isQ ? Q : K) + rowoff;
    ushort* yb = (isQ ? Qb16 : Kb16) + rowoff;
    double acc[MM];
#pragma unroll
    for (int m = 0; m < MM; ++m) acc[m] = 0.0;
#pragma unroll
    for (int j = 0; j < 8; ++j) {
        int i = j * 64 + lane;
        float xv = x[i];
        yb[i] = f2b(xv);
#pragma unroll
        for (int m = 0; m < MM; ++m) acc[m] += (double)xv * (double)miu[m*DD + i];
    }
#pragma unroll
    for (int m = 0; m < MM; ++m) {
#pragma unroll
        for (int off = 32; off > 0; off >>= 1)
            acc[m] += __shfl_down(acc[m], off);
    }
    if (lane == 0) {
        double best = acc[0]; int bi = 0;
#pragma unroll
        for (int m = 1; m < MM; ++m) if (acc[m] > best) { best = acc[m]; bi = m; }
        if (isQ) aq[b*SQL + t] = bi; else ak[b*SKL + (t - SQL)] = bi;
    }
}

// ---------------- stable compaction into per-(b,m) index lists ----------------
__global__ void k_compact(const int* __restrict__ aq, const int* __restrict__ ak,
                          int* __restrict__ qcnt, int* __restrict__ kcnt,
                          int* __restrict__ qlist, int* __restrict__ klist) {
    int idx = blockIdx.x;
    int isK = idx >> 5;
    int g   = idx & 31;
    int b = g >> 3, m = g & 7;
    const int* a = isK ? (ak + b*SKL) : (aq + b*SQL);
    int* list = (isK ? klist : qlist) + g*SQL;
    int lane = threadIdx.x;
    int base = 0;
    for (int c = 0; c < SQL; c += 64) {
        int s = c + lane;
        bool f = (a[s] == m);
        unsigned long long mk = __ballot(f);
        int before = __popcll(mk & ((1ull << lane) - 1ull));
        if (f) list[base + before] = s;
        base += __popcll(mk);
    }
    if (lane == 0) (isK ? kcnt : qcnt)[g] = base;
}

// ---------------- offsets + compact tile work-lists ----------------
__global__ void k_soff(const int* __restrict__ qcnt, const int* __restrict__ kcnt,
                       int* __restrict__ soff, int* __restrict__ pboff,
                       int* __restrict__ qoff, int* __restrict__ koff,
                       int* __restrict__ tkoff, int* __restrict__ counts,
                       int* __restrict__ projl, int* __restrict__ scl,
                       int* __restrict__ pvl) {
    __shared__ int pbase[64], sbase[32], pvbase[32];
    int lane = threadIdx.x;
    if (lane == 0) {
        int sacc = 0, pacc = 0, qa = 0, ka = 0, ta = 0;
        for (int g = 0; g < NG; ++g) {
            soff[g] = sacc; pboff[g] = pacc; qoff[g] = qa; koff[g] = ka; tkoff[g] = ta;
            int nq = qcnt[g], nk = kcnt[g];
            int nks = ((nk + 63) & ~63) + 32;
            sacc += nq * nk; pacc += nq * nks; qa += nq; ka += nk; ta += DD * nks;
        }
        soff[NG] = sacc; pboff[NG] = pacc; qoff[NG] = qa; koff[NG] = ka; tkoff[NG] = ta;
        int pj = 0, sc = 0, pv = 0;
        for (int sg = 0; sg < 64; ++sg) {
            int n = (sg >= 32 ? kcnt : qcnt)[sg & 31];
            pbase[sg] = pj; pj += (n + 127) >> 7;     // 128-token proj tiles
        }
        for (int g = 0; g < NG; ++g) {
            int nq = qcnt[g], nk = kcnt[g];
            sbase[g] = sc; pvbase[g] = pv;
            if (nq > 0 && nk > 0) {
                sc += ((nq + 63) >> 6) * ((nk + 63) >> 6);
                pv += (nq + 31) >> 5;                 // 32-row pv tiles
            }
        }
        counts[0] = pj; counts[1] = sc; counts[2] = pv;
    }
    __syncthreads();
    {   // proj tiles: one (side,g) per lane
        int sg = lane;
        int side = sg >> 5, g = sg & 31;
        int n = (side ? kcnt : qcnt)[g];
        int ntile = (n + 127) >> 7;
        int base = pbase[sg];
        for (int ty = 0; ty < ntile; ++ty)
            projl[base + ty] = (side << 11) | (g << 6) | ty;
    }
    if (lane < 32) {   // scores + pv tiles: one g per lane (group-contiguous order)
        int g = lane;
        int nq = qcnt[g], nk = kcnt[g];
        if (nq > 0 && nk > 0) {
            int nqt = (nq + 63) >> 6, nkt = (nk + 63) >> 6;
            int idx = sbase[g];
            for (int qy = 0; qy < nqt; ++qy)
                for (int ky = 0; ky < nkt; ++ky)
                    scl[idx++] = (g << 10) | (qy << 5) | ky;
            int nqt32 = (nq + 31) >> 5;
            int pidx = pvbase[g];
            for (int qy = 0; qy < nqt32; ++qy)
                pvl[pidx++] = (g << 7) | qy;          // qy fits 7 bits (<= 64)
        }
    }
}

// W[m][d][e] (f32) -> Wt[m][e][d] (bf16), tiled transpose
__global__ void k_cvtW(const float* __restrict__ Wq, const float* __restrict__ Wk,
                       ushort* __restrict__ Wqt, ushort* __restrict__ Wkt) {
    __shared__ float tile[32][33];
    int mm = blockIdx.x; int isK = mm >> 3; int m = mm & 7;
    const float* W = (isK ? Wk : Wq) + (size_t)m * DD * DD;
    ushort* Wt = (isK ? Wkt : Wqt) + (size_t)m * DD * DD;
    int d0 = blockIdx.y * 32, e0 = blockIdx.z * 32;
    int tx = threadIdx.x, ty = threadIdx.y;   // 32 x 8
    for (int i = ty; i < 32; i += 8)
        tile[i][tx] = W[(size_t)(d0 + i) * DD + e0 + tx];
    __syncthreads();
    for (int i = ty; i < 32; i += 8)
        Wt[(size_t)(e0 + i) * DD + d0 + tx] = f2b(tile[tx][i]);
}

// ---------------- grouped expert projection: raw-barrier pipeline (counted vmcnt) ----------------
// Per K-step: issue next stage's 8 global_load_lds; s_waitcnt vmcnt(8) waits only
// the PREVIOUS stage (next stays in flight across MFMA); raw s_barrier (no drain).
__global__ __launch_bounds__(256) void k_proj_mfma(
        const ushort* __restrict__ Qb16, const ushort* __restrict__ Kb16,
        const ushort* __restrict__ Wqt, const ushort* __restrict__ Wkt,
        const float* __restrict__ bq, const float* __restrict__ bk,
        const int* __restrict__ qcnt, const int* __restrict__ kcnt,
        const int* __restrict__ qlist, const int* __restrict__ klist,
        const int* __restrict__ qoff, const int* __restrict__ koff,
        const int* __restrict__ tkoff, const int* __restrict__ counts,
        const int* __restrict__ projl,
        ushort* __restrict__ Qc, ushort* __restrict__ Kc, ushort* __restrict__ KcT) {
    __shared__ ushort lds[2][16384];          // per buf: As[128][64] | Bs[128][64]
    __shared__ int rows[128];
    int tid = threadIdx.x;
    int wid = tid >> 6, lane = tid & 63;
    int wr = wid >> 1, wc = wid & 1;
    int lr = lane & 15;
    int h = lane >> 4;                        // 0..3 (k-slot)
    int x7 = lr & 7;                          // read-side swizzle key
    int csz0 = ((h ^ x7) << 3);               // swizzled read col (ushorts), kk=0
    int csz1 = (((4 | h) ^ x7) << 3);         // kk=1
    int c0 = blockIdx.y * 128;
    int e8 = lane >> 3;                       // stage: row-within-chunk
    int glcs = (((lane & 7) ^ e8) << 3);      // stage: PRE-SWIZZLED source col (ushorts)
    int cnt = counts[0];
    int vbid = (blockIdx.x & 7) * 24 + (blockIdx.x >> 3);   // XCD-chunked (192 blocks)

    for (int slot = vbid; slot < cnt; slot += gridDim.x) {
        int e = projl[slot];
        int isK = (e >> 11) & 1, g = (e >> 6) & 31, ty = e & 63;
        int n = (isK ? kcnt : qcnt)[g];
        int obase = (isK ? koff : qoff)[g];
        int b = g >> 3, m = g & 7;
        const ushort* Xtok = (isK ? Kb16 : Qb16) + (size_t)b * SQL * DD;
        const ushort* Wt = (isK ? Wkt : Wqt) + (size_t)m * DD * DD;
        const float* bias = (isK ? bk : bq) + m * DD;
        const int* list = (isK ? klist : qlist) + g * SQL;
        int t0 = ty * 128;

        __syncthreads();                      // prev slot done with rows[] + LDS
        if (tid < 128) rows[tid] = list[min(t0 + tid, n - 1)];
        __syncthreads();

        auto STAGE = [&](int buf, int kt) {   // 8 global_load_lds per thread
            int d0 = kt * 64;
            ushort* As = lds[buf];
            ushort* Bs = lds[buf] + 8192;
#pragma unroll
            for (int j0 = 0; j0 < 4; ++j0) {
                int j = wid + j0 * 4;         // chunk 0..15 (8 rows each)
                int rtok = rows[j*8 + e8];
                gload16(Xtok + (size_t)rtok * DD + d0 + glcs, As + j*512);
                int rB = c0 + j*8 + e8;
                gload16(Wt + (size_t)rB * DD + d0 + glcs, Bs + j*512);
            }
        };

        f32x4 acc[4][4];
#pragma unroll
        for (int t = 0; t < 4; ++t)
#pragma unroll
            for (int c = 0; c < 4; ++c) acc[t][c] = (f32x4){0.f, 0.f, 0.f, 0.f};

        STAGE(0, 0);
        for (int kt = 0; kt < 8; ++kt) {
            int cur = kt & 1;
            if (kt < 7) {
                STAGE(cur ^ 1, kt + 1);       // issue next stage (stays in flight)
                asm volatile("s_waitcnt vmcnt(8)" ::: "memory");  // prev stage landed
            } else {
                asm volatile("s_waitcnt vmcnt(0)" ::: "memory");  // last stage landed
            }
            __builtin_amdgcn_s_barrier();     // raw barrier: no vmcnt drain
            const ushort* As = lds[cur];
            const ushort* Bs = lds[cur] + 8192;
#pragma unroll
            for (int kk = 0; kk < 2; ++kk) {
                int csz = kk ? csz1 : csz0;
                short8v a[4], bb[4];
#pragma unroll
                for (int t = 0; t < 4; ++t)
                    a[t] = *(const short8v*)(As + (wr*64 + t*16 + lr)*64 + csz);
#pragma unroll
                for (int c = 0; c < 4; ++c)
                    bb[c] = *(const short8v*)(Bs + (wc*64 + c*16 + lr)*64 + csz);
#pragma unroll
                for (int t = 0; t < 4; ++t)
#pragma unroll
                    for (int c = 0; c < 4; ++c)
                        acc[t][c] = __builtin_amdgcn_mfma_f32_16x16x32_bf16(a[t], bb[c], acc[t][c], 0, 0, 0);
            }
            __builtin_amdgcn_s_barrier();     // all waves done reading buf cur
        }

        float bcache[4];
#pragma unroll
        for (int c = 0; c < 4; ++c) bcache[c] = bias[c0 + wc*64 + c*16 + lr];

        int rb = (lane >> 4) << 2;
        int nk2 = kcnt[g];
        int nks = ((nk2 + 63) & ~63) + 32;    // 64-aligned + skewed KcT row stride
        int tk = tkoff[g];
        ushort* Yc = isK ? Kc : Qc;
#pragma unroll
        for (int t = 0; t < 4; ++t) {
            int grow = ty*128 + wr*64 + t*16 + rb;   // group-relative row of r=0
#pragma unroll
            for (int c = 0; c < 4; ++c) {
                int col = c0 + wc*64 + c*16 + lr;
                float v[4];
#pragma unroll
                for (int r = 0; r < 4; ++r) v[r] = gelu_fast(acc[t][c][r] + bcache[c]);
                if (!isK) {
#pragma unroll
                    for (int r = 0; r < 4; ++r)
                        if (grow + r < n)
                            Yc[(size_t)(obase + grow + r) * DD + col] = f2b(v[r] * SCALE);
                } else {
#pragma unroll
                    for (int r = 0; r < 4; ++r)
                        if (grow + r < n)
                            Yc[(size_t)(obase + grow + r) * DD + col] = f2b(v[r]);
                    size_t taddr = (size_t)tk + (size_t)col * nks + grow;
                    if (grow + 3 < n) {
                        ushort4 o; o.x = f2b(v[0]); o.y = f2b(v[1]); o.z = f2b(v[2]); o.w = f2b(v[3]);
                        *(ushort4*)(KcT + taddr) = o;
                    } else {
#pragma unroll
                        for (int r = 0; r < 4; ++r)
                            if (grow + r < n) KcT[taddr + r] = f2b(v[r]);
                    }
                }
            }
        }
    }
}

// ---------------- mean of Kp over all keys (fallback value), two-stage ----------------
__global__ void k_meanpart(const ushort* __restrict__ Kc, const int* __restrict__ koff,
                           float* __restrict__ part) {
    int b = blockIdx.x, ch = blockIdx.y;      // 32 chunks of 64 rows
    int d = threadIdx.x;                      // 256 threads -> 2 cols each
    int base = koff[b*8] + ch * 64;
    float a0 = 0.f, a1 = 0.f;
    for (int t = 0; t < 64; ++t) {
        const ushort* row = Kc + (size_t)(base + t) * DD;
        a0 += b2f(row[d]); a1 += b2f(row[d + 256]);
    }
    part[((size_t)(b*32 + ch))*DD + d]       = a0;
    part[((size_t)(b*32 + ch))*DD + d + 256] = a1;
}
__global__ void k_meanfinal(const float* __restrict__ part, float* __restrict__ meanV) {
    int b = blockIdx.x; int d = threadIdx.x;  // 512 threads
    float a0 = 0.f;
    for (int ch = 0; ch < 32; ++ch)
        a0 += part[((size_t)(b*32 + ch))*DD + d];
    meanV[b*DD + d] = a0 * (1.0f/SKL);
}

// ---------------- grouped scores S = Qc @ Kc^T: LDS-staged (TA-coalesced) ----------------
__global__ __launch_bounds__(256) void k_scores_mfma(
        const ushort* __restrict__ Qc, const ushort* __restrict__ Kc,
        const int* __restrict__ qcnt, const int* __restrict__ kcnt,
        const int* __restrict__ qoff, const int* __restrict__ koff,
        const int* __restrict__ soff, const int* __restrict__ counts,
        const int* __restrict__ scl, float* __restrict__ S) {
    __shared__ ushort lds[2][8192];           // per buf: As[64][64] | Bs[64][64]
    int tid = threadIdx.x, wid = tid >> 6, lane = tid & 63;
    int wr = wid >> 1, wc = wid & 1;
    int lr = lane & 15;
    int h  = lane >> 4;
    int x7 = lr & 7;
    int csz0 = ((h ^ x7) << 3);
    int csz1 = (((4 | h) ^ x7) << 3);
    int e8 = lane >> 3;                       // row-within-chunk (0..7)
    int glcs = (((lane & 7) ^ e8) << 3);      // pre-swizzled source col (ushorts)
    int cnt = counts[1];
    int vbid = (blockIdx.x & 7) * 128 + (blockIdx.x >> 3);  // XCD-chunked (1024 blocks)
    for (int slot = vbid; slot < cnt; slot += gridDim.x) {
        int e = scl[slot];
        int g = (e >> 10) & 31, qt = ((e >> 5) & 31) * 64, kt = (e & 31) * 64;
        int nq = qcnt[g], nk = kcnt[g];
        int qb = qoff[g], kb = koff[g];

        auto STAGE = [&](int buf, int dstep) {
            int d0 = dstep * 64;
            ushort* As = lds[buf];
            ushort* Bs = lds[buf] + 4096;
#pragma unroll
            for (int j0 = 0; j0 < 4; ++j0) {
                int j = wid + j0 * 4;         // 0..15: A chunks 0-7, B chunks 8-15
                if (j < 8) {
                    int r = qb + min(qt + j*8 + e8, nq - 1);
                    gload16(Qc + (size_t)r * DD + d0 + glcs, As + j*512);
                } else {
                    int jb = j - 8;
                    int r = kb + min(kt + jb*8 + e8, nk - 1);
                    gload16(Kc + (size_t)r * DD + d0 + glcs, Bs + jb*512);
                }
            }
        };

        f32x4 acc[2][2];
#pragma unroll
        for (int t = 0; t < 2; ++t)
#pragma unroll
            for (int c = 0; c < 2; ++c) acc[t][c] = (f32x4){0.f, 0.f, 0.f, 0.f};

        __syncthreads();                      // prev slot done with LDS
        STAGE(0, 0);
        __syncthreads();
        for (int ds = 0; ds < 8; ++ds) {
            int cur = ds & 1;
            if (ds < 7) STAGE(cur ^ 1, ds + 1);   // prefetch next d-step
            const ushort* As = lds[cur];
            const ushort* Bs = lds[cur] + 4096;
#pragma unroll
            for (int kk = 0; kk < 2; ++kk) {
                int csz = kk ? csz1 : csz0;
                short8v a[2], bb[2];
#pragma unroll
                for (int t = 0; t < 2; ++t)
                    a[t] = *(const short8v*)(As + (wr*32 + t*16 + lr)*64 + csz);
#pragma unroll
                for (int c = 0; c < 2; ++c)
                    bb[c] = *(const short8v*)(Bs + (wc*32 + c*16 + lr)*64 + csz);
#pragma unroll
                for (int t = 0; t < 2; ++t)
#pragma unroll
                    for (int c = 0; c < 2; ++c)
                        acc[t][c] = __builtin_amdgcn_mfma_f32_16x16x32_bf16(a[t], bb[c], acc[t][c], 0, 0, 0);
            }
            __syncthreads();                  // prefetch drained; buf swap safe
        }

        int sbase = soff[g];
        int rb = (lane >> 4) << 2;
#pragma unroll
        for (int t = 0; t < 2; ++t) {
#pragma unroll
            for (int r = 0; r < 4; ++r) {
                int gr = qt + wr*32 + t*16 + rb + r;
                if (gr >= nq) continue;
#pragma unroll
                for (int c = 0; c < 2; ++c) {
                    int gc = kt + wc*32 + c*16 + lr;
                    if (gc < nk) S[(size_t)sbase + (size_t)gr*nk + gc] = acc[t][c][r];
                }
            }
        }
    }
}

// ---------------- softmax rows -> bf16 probs, zero-padded to nk64, skewed stride ----------------
__global__ void k_softmax(const int* __restrict__ qcnt, const int* __restrict__ kcnt,
                          const int* __restrict__ soff, const int* __restrict__ pboff,
                          float* __restrict__ S, ushort* __restrict__ Pb) {
    int g = blockIdx.x;
    int nq = qcnt[g], nk = kcnt[g];
    if (nk == 0) return;
    int wid = threadIdx.x >> 6, lane = threadIdx.x & 63;
    int nk64 = (nk + 63) & ~63;
    int nks = nk64 + 32;
    for (int row = blockIdx.y * 16 + wid; row < nq; row += 512) {
        float* p = S + (size_t)soff[g] + (size_t)row * nk;
        ushort* pr = Pb + (size_t)pboff[g] + (size_t)row * nks;
        float mx = -3.4e38f;
        for (int c = lane; c < nk; c += 64) mx = fmaxf(mx, p[c]);
#pragma unroll
        for (int off = 32; off > 0; off >>= 1) mx = fmaxf(mx, __shfl_xor(mx, off));
        float sm = 0.f;
        for (int c = lane; c < nk; c += 64) { float e = __expf(p[c] - mx); p[c] = e; sm += e; }
#pragma unroll
        for (int off = 32; off > 0; off >>= 1) sm += __shfl_xor(sm, off);
        float inv = 1.0f / sm;
        for (int c = lane; c < nk64; c += 64) {
            float v = (c < nk) ? p[c] * inv : 0.f;
            pr[c] = f2b(v);
        }
    }
}

// ---------------- PV: O = P @ Kc via KcT, LDS-staged bf16 MFMA, epilogue += Q ----------------
__global__ __launch_bounds__(256) void k_pv_mfma(
        const ushort* __restrict__ Pb, const ushort* __restrict__ KcT,
        const float* __restrict__ Q,
        const int* __restrict__ qcnt, const int* __restrict__ kcnt,
        const int* __restrict__ tkoff, const int* __restrict__ pboff,
        const int* __restrict__ qlist, const int* __restrict__ counts,
        const int* __restrict__ pvl, float* __restrict__ out) {
    __shared__ ushort plds[2][2048];          // 32 rows x 64 keys
    __shared__ ushort klds[2][8192];          // 128 cols x 64 keys
    int tid = threadIdx.x, wid = tid >> 6, lane = tid & 63;
    int lr = lane & 15;
    int h  = lane >> 4;
    int x7 = lr & 7;
    int csz0 = ((h ^ x7) << 3);
    int csz1 = (((4 | h) ^ x7) << 3);
    int e8 = lane >> 3;                       // row-within-chunk (0..7)
    int glcs = (((lane & 7) ^ e8) << 3);      // pre-swizzled source col (ushorts)
    int cnt = counts[2];
    int vbid = (blockIdx.x & 7) * 32 + (blockIdx.x >> 3);   // XCD-chunked (256 blocks)
    int dt = blockIdx.y * 128;

    for (int slot = vbid; slot < cnt; slot += gridDim.x) {
        int e = pvl[slot];
        int g = e >> 7, qt = (e & 127) * 32;
        int nq = qcnt[g], nk = kcnt[g];
        int b = g >> 3;
        int nk64 = (nk + 63) & ~63;
        int nks = nk64 + 32;
        int tk = tkoff[g], pbase = pboff[g];

        const ushort* psrc = Pb + (size_t)pbase
            + (size_t)min(qt + wid*8 + e8, nq - 1) * nks + glcs;
        const ushort* ksrc[4];
#pragma unroll
        for (int p = 0; p < 4; ++p) {
            int col = (wid + p*4) * 8 + e8;   // 0..127
            ksrc[p] = KcT + (size_t)tk + (size_t)(dt + col) * nks + glcs;
        }

        auto STAGE = [&](int buf, int kt) {
            int k0 = kt * 64;
            gload16(psrc + k0, &plds[buf][wid * 512]);
#pragma unroll
            for (int p = 0; p < 4; ++p)
                gload16(ksrc[p] + k0, &klds[buf][(wid + p*4) * 512]);
        };

        f32x4 acc[2][2];
#pragma unroll
        for (int t = 0; t < 2; ++t)
#pragma unroll
            for (int c = 0; c < 2; ++c) acc[t][c] = (f32x4){0.f, 0.f, 0.f, 0.f};

        int nt = nk64 >> 6;
        __syncthreads();                      // prev slot done with LDS
        STAGE(0, 0);
        __syncthreads();
        for (int kt = 0; kt < nt; ++kt) {
            int cur = kt & 1;
            if (kt + 1 < nt) STAGE(cur ^ 1, kt + 1);
            const ushort* P_ = plds[cur];
            const ushort* K_ = klds[cur];
#pragma unroll
            for (int kk = 0; kk < 2; ++kk) {
                int csz = kk ? csz1 : csz0;
                short8v a[2], bb[2];
#pragma unroll
                for (int t = 0; t < 2; ++t)
                    a[t] = *(const short8v*)(P_ + (t*16 + lr)*64 + csz);
#pragma unroll
                for (int c = 0; c < 2; ++c)
                    bb[c] = *(const short8v*)(K_ + (wid*32 + c*16 + lr)*64 + csz);
#pragma unroll
                for (int t = 0; t < 2; ++t)
#pragma unroll
                    for (int c = 0; c < 2; ++c)
                        acc[t][c] = __builtin_amdgcn_mfma_f32_16x16x32_bf16(a[t], bb[c], acc[t][c], 0, 0, 0);
            }
            __syncthreads();                  // prefetch drained; buf swap safe
        }

        int rb = (lane >> 4) << 2;
#pragma unroll
        for (int t = 0; t < 2; ++t) {
#pragma unroll
            for (int r = 0; r < 4; ++r) {
                int gr = qt + t*16 + rb + r;
                if (gr >= nq) continue;
                int qrow = qlist[g*SQL + gr];
                size_t obase = ((size_t)(b*SQL) + qrow) * DD;
#pragma unroll
                for (int c = 0; c < 2; ++c) {
                    size_t o = obase + dt + wid*32 + c*16 + lr;
                    out[o] = acc[t][c][r] + Q[o];
                }
            }
        }
    }
}

// ---------------- fallback for groups with no keys: O = mean(Kp) + Q ----------------
__global__ void k_fallback(const float* __restrict__ Q, const float* __restrict__ meanV,
                           const int* __restrict__ qcnt, const int* __restrict__ kcnt,
                           const int* __restrict__ qlist, float* __restrict__ out) {
    int g = blockIdx.x;
    if (kcnt[g] != 0) return;
    int nq = qcnt[g]; int b = g >> 3;
    int r0 = blockIdx.y * 256;
    int rend = min(r0 + 256, nq);
    for (int r = r0; r < rend; ++r) {
        int qrow = qlist[g*SQL + r];
        size_t base = ((size_t)(b*SQL) + qrow) * DD;
        for (int d = threadIdx.x; d < DD; d += 256)
            out[base + d] = meanV[b*DD + d] + Q[base + d];
    }
}

extern "C" void kernel_launch(void* const* d_in, const int* in_sizes, int n_in,
                              void* d_out, int out_size, void* d_ws, size_t ws_size,
                              hipStream_t stream) {
    (void)in_sizes; (void)n_in; (void)out_size; (void)ws_size;
    const float* Q   = (const float*)d_in[0];
    const float* K   = (const float*)d_in[1];
    // d_in[2] (V) unused: Vp == Kp in the reference.
    const float* miu = (const float*)d_in[3];
    const float* Wq  = (const float*)d_in[4];
    const float* bq  = (const float*)d_in[5];
    const float* Wk  = (const float*)d_in[6];
    const float* bk  = (const float*)d_in[7];
    float* out = (float*)d_out;
    char* ws = (char*)d_ws;

    size_t off = 0;
    auto alloc = [&](size_t bytes) { size_t o = off; off += (bytes + 255) & ~(size_t)255; return o; };
    int*   aq     = (int*)  (ws + alloc((size_t)BB*SQL*4));
    int*   ak     = (int*)  (ws + alloc((size_t)BB*SKL*4));
    int*   qcnt   = (int*)  (ws + alloc(NG*4));
    int*   kcnt   = (int*)  (ws + alloc(NG*4));
    int*   soff   = (int*)  (ws + alloc((NG+1)*4));
    int*   pboff  = (int*)  (ws + alloc((NG+1)*4));
    int*   qoff   = (int*)  (ws + alloc((NG+1)*4));
    int*   koff   = (int*)  (ws + alloc((NG+1)*4));
    int*   tkoff  = (int*)  (ws + alloc((NG+1)*4));
    int*   counts = (int*)  (ws + alloc(16*4));
    int*   projl  = (int*)  (ws + alloc(PROJCAP*4));
    int*   scl    = (int*)  (ws + alloc(SCCAP*4));
    int*   pvl    = (int*)  (ws + alloc(PVCAP*4));
    int*   qlist  = (int*)  (ws + alloc((size_t)NG*SQL*4));
    int*   klist  = (int*)  (ws + alloc((size_t)NG*SKL*4));
    float* part   = (float*)(ws + alloc((size_t)BB*32*DD*4));
    float* meanV  = (float*)(ws + alloc((size_t)BB*DD*4));
    ushort* Qc    = (ushort*)(ws + alloc((size_t)BB*SQL*DD*2));
    ushort* Kc    = (ushort*)(ws + alloc((size_t)BB*SKL*DD*2));
    ushort* KcT   = (ushort*)(ws + alloc(KTCAP*2));
    ushort* Pb    = (ushort*)(ws + alloc((size_t)PCAP*2));
    // Union region (34 MB): bf16 staging Wqt|Wkt|Qb16|Kb16 (dead after proj), then S (f32).
    size_t uoff = alloc((size_t)UCAP);
    float* S     = (float*)(ws + uoff);
    ushort* Wqt  = (ushort*)(ws + uoff);
    ushort* Wkt  = Wqt  + (size_t)MM*DD*DD;
    ushort* Qb16 = Wkt  + (size_t)MM*DD*DD;
    ushort* Kb16 = Qb16 + (size_t)BB*SQL*DD;

    k_route     <<<NTOK/4, 256, 0, stream>>>(Q, K, miu, aq, ak, Qb16, Kb16);
    k_compact   <<<NG*2, 64, 0, stream>>>(aq, ak, qcnt, kcnt, qlist, klist);
    k_soff      <<<1, 64, 0, stream>>>(qcnt, kcnt, soff, pboff, qoff, koff, tkoff,
                                       counts, projl, scl, pvl);
    k_cvtW      <<<dim3(16, 16, 16), dim3(32, 8), 0, stream>>>(Wq, Wk, Wqt, Wkt);
    k_proj_mfma <<<dim3(192, 4), 256, 0, stream>>>(Qb16, Kb16, Wqt, Wkt, bq, bk,
                                                   qcnt, kcnt, qlist, klist, qoff, koff,
                                                   tkoff, counts, projl, Qc, Kc, KcT);
    k_meanpart  <<<dim3(BB, 32), 256, 0, stream>>>(Kc, koff, part);
    k_meanfinal <<<BB, 512, 0, stream>>>(part, meanV);
    k_scores_mfma<<<1024, 256, 0, stream>>>(Qc, Kc, qcnt, kcnt, qoff, koff, soff,
                                            counts, scl, S);
    k_softmax   <<<dim3(NG, 32), 1024, 0, stream>>>(qcnt, kcnt, soff, pboff, S, Pb);
    k_pv_mfma   <<<dim3(256, 4), 256, 0, stream>>>(Pb, KcT, Q, qcnt, kcnt, tkoff, pboff,
                                                   qlist, counts, pvl, out);
    k_fallback  <<<dim3(NG, 8), 256, 0, stream>>>(Q, meanV, qcnt, kcnt, qlist, out);
}